// Round 3
// baseline (1382.742 us; speedup 1.0000x reference)
//
#include <hip/hip_runtime.h>
#include <hip/hip_bf16.h>
#include <math.h>

using bf16 = __hip_bfloat16;

typedef __attribute__((ext_vector_type(8))) short short8;
typedef __attribute__((ext_vector_type(4))) float floatx4;

#define D_MODEL 1024
#define D_STATE 16
#define D_FFN   4096
#define D_INNER 2048
#define DT_RANK 64
#define BSZ     2
#define SEQ     2048
#define MROWS   (BSZ*SEQ)   /* 4096 */

static __device__ __forceinline__ float bf2f(bf16 v) { return __bfloat162float(v); }
static __device__ __forceinline__ short f2s(float f) {
    bf16 h = __float2bfloat16(f);
    return *reinterpret_cast<short*>(&h);
}

// 8-element loaders -> bf16 bits (short8)
static __device__ __forceinline__ short8 load8(const bf16* p) {
    return *(const short8*)p;
}
static __device__ __forceinline__ short8 load8(const float* p) {
    float4 a = *(const float4*)p;
    float4 b = *(const float4*)(p + 4);
    short8 r;
    r[0] = f2s(a.x); r[1] = f2s(a.y); r[2] = f2s(a.z); r[3] = f2s(a.w);
    r[4] = f2s(b.x); r[5] = f2s(b.y); r[6] = f2s(b.z); r[7] = f2s(b.w);
    return r;
}
static __device__ __forceinline__ float rd(const bf16* p)  { return bf2f(*p); }
static __device__ __forceinline__ float rd(const float* p) { return *p; }
static __device__ __forceinline__ void  wr(bf16* p, float v)  { *p = __float2bfloat16(v); }
static __device__ __forceinline__ void  wr(float* p, float v) { *p = v; }

// ---------------------------------------------------------------------------
// GEMM: C[M,N] = act(A[M,K] @ W[N,K]^T + bias) (+ resid). f32 or bf16 inputs
// (converted to bf16 at LDS staging), f32 accum via mfma_f32_16x16x32_bf16.
// 128x128 tile, BK=32, 256 thr = 4 waves (2x2), each wave 64x64 as 4x4 MFMAs.
// ---------------------------------------------------------------------------
#define BM 128
#define BN 128
#define BK 32
#define LDSS 40

enum { ACT_NONE = 0, ACT_GELU = 1, ACT_SOFTPLUS = 2 };

template<int ACT, bool HAS_BIAS, bool HAS_RES,
         typename TA, typename TW, typename TR, typename TC>
__global__ __launch_bounds__(256)
void gemm_bt(const TA* __restrict__ A, int lda,
             const TW* __restrict__ W,
             TC* __restrict__ C, int ldc,
             const float* __restrict__ bias,
             const TR* __restrict__ resid, int ldr,
             int K)
{
    __shared__ __align__(16) bf16 As[BM * LDSS];
    __shared__ __align__(16) bf16 Bs[BN * LDSS];

    const int tid  = threadIdx.x;
    const int lane = tid & 63;
    const int wid  = tid >> 6;
    const int wm   = wid >> 1;
    const int wn   = wid & 1;
    const int quad = lane >> 4;
    const int lrow = lane & 15;

    const long m0 = (long)blockIdx.y * BM;
    const long n0 = (long)blockIdx.x * BN;

    const int c0 = tid, c1 = tid + 256;
    const int r0 = c0 >> 2, o0 = (c0 & 3) * 8;
    const int r1 = c1 >> 2, o1 = (c1 & 3) * 8;

    const TA* Ag0 = A + (m0 + r0) * (long)lda + o0;
    const TA* Ag1 = A + (m0 + r1) * (long)lda + o1;
    const TW* Wg0 = W + (n0 + r0) * (long)K + o0;
    const TW* Wg1 = W + (n0 + r1) * (long)K + o1;

    floatx4 acc[4][4] = {};

    for (int k0 = 0; k0 < K; k0 += BK) {
        short8 a0 = load8(Ag0 + k0);
        short8 a1 = load8(Ag1 + k0);
        short8 b0 = load8(Wg0 + k0);
        short8 b1 = load8(Wg1 + k0);
        __syncthreads();
        *(short8*)(As + r0 * LDSS + o0) = a0;
        *(short8*)(As + r1 * LDSS + o1) = a1;
        *(short8*)(Bs + r0 * LDSS + o0) = b0;
        *(short8*)(Bs + r1 * LDSS + o1) = b1;
        __syncthreads();

        short8 af[4], bfv[4];
        #pragma unroll
        for (int i = 0; i < 4; i++)
            af[i] = *(const short8*)(As + (wm * 64 + i * 16 + lrow) * LDSS + quad * 8);
        #pragma unroll
        for (int j = 0; j < 4; j++)
            bfv[j] = *(const short8*)(Bs + (wn * 64 + j * 16 + lrow) * LDSS + quad * 8);
        #pragma unroll
        for (int i = 0; i < 4; i++)
            #pragma unroll
            for (int j = 0; j < 4; j++)
                acc[i][j] = __builtin_amdgcn_mfma_f32_16x16x32_bf16(af[i], bfv[j], acc[i][j], 0, 0, 0);
    }

    // epilogue: D row = quad*4 + r, col = lrow (verified m89 C/D layout)
    #pragma unroll
    for (int j = 0; j < 4; j++) {
        const long col = n0 + wn * 64 + j * 16 + lrow;
        float bv = HAS_BIAS ? bias[col] : 0.0f;
        #pragma unroll
        for (int i = 0; i < 4; i++) {
            #pragma unroll
            for (int r = 0; r < 4; r++) {
                const long row = m0 + wm * 64 + i * 16 + quad * 4 + r;
                float v = acc[i][j][r] + bv;
                if (ACT == ACT_GELU)     v = 0.5f * v * (1.0f + erff(v * 0.70710678118f));
                if (ACT == ACT_SOFTPLUS) v = (v > 20.0f) ? v : log1pf(__expf(v));
                if (HAS_RES) v += rd(resid + row * (long)ldr + col);
                wr(C + row * (long)ldc + col, v);
            }
        }
    }
}

// ---------------------------------------------------------------------------
// depthwise causal conv (K=3) + bias + silu: xpre (M,2048) bf16 -> xp bf16
// ---------------------------------------------------------------------------
__global__ __launch_bounds__(256)
void conv_silu(const bf16* __restrict__ xpre, const float* __restrict__ cw,
               const float* __restrict__ cb, bf16* __restrict__ xp)
{
    long i = (long)blockIdx.x * 256 + threadIdx.x;   // MROWS*D_INNER
    int  d  = (int)(i & (D_INNER - 1));
    long bl = i >> 11;
    long l  = bl & (SEQ - 1);

    float w0 = cw[d * 3 + 0];
    float w1 = cw[d * 3 + 1];
    float w2 = cw[d * 3 + 2];
    float acc = cb[d] + w2 * bf2f(xpre[i]);
    if (l >= 1) acc += w1 * bf2f(xpre[i - D_INNER]);
    if (l >= 2) acc += w0 * bf2f(xpre[i - 2 * D_INNER]);
    float s = acc / (1.0f + __expf(-acc));
    xp[i] = __float2bfloat16(s);
}

// ---------------------------------------------------------------------------
// pad x_proj_w (96,2048) f32 -> (128,2048) bf16 with zero rows
// ---------------------------------------------------------------------------
__global__ __launch_bounds__(256)
void pad_xproj(const float* __restrict__ src, bf16* __restrict__ dst)
{
    int i = blockIdx.x * 256 + threadIdx.x;   // 128*2048
    int row = i >> 11, col = i & 2047;
    dst[i] = (row < 96) ? __float2bfloat16(src[row * 2048 + col])
                        : __float2bfloat16(0.0f);
}

// ---------------------------------------------------------------------------
// SSM scan + fused gating. block = 256 thr = 16 d x 16 n. 256 blocks (b,d/16).
// Gated y written IN-PLACE into xp (reads of a row provably precede its write
// via the shfl data dependence). h_final -> state (f32, part of d_out).
// ---------------------------------------------------------------------------
__global__ __launch_bounds__(256)
void ssm_scan(const bf16* __restrict__ dt, bf16* __restrict__ xp,
              const bf16* __restrict__ dbc, const float* __restrict__ Alog,
              const bf16* __restrict__ z, const float* __restrict__ Dp,
              float* __restrict__ state)
{
    const int tid = threadIdx.x;
    const int n   = tid & 15;
    const int dl  = tid >> 4;
    const int b   = blockIdx.x >> 7;
    const int d   = ((blockIdx.x & 127) << 4) + dl;

    const float Ad  = -__expf(Alog[d * 16 + n]);
    const float Dpd = Dp[d];
    float h = 0.0f;
    const long rowb = (long)b * SEQ;

    float dt0[8], x0[8], B0[8], C0[8], z0[8];
    float dt1[8], x1v[8], B1[8], C1[8], z1[8];

    auto ld = [&](int l0, float* dtv, float* xv, float* Bv, float* Cv, float* zv) {
        #pragma unroll
        for (int j = 0; j < 8; j++) {
            long r = (rowb + l0 + j) * (long)D_INNER + d;
            dtv[j] = bf2f(dt[r]);
            xv[j]  = bf2f(xp[r]);
            zv[j]  = bf2f(z[r]);
            long r2 = (rowb + l0 + j) * 128;
            Bv[j]  = bf2f(dbc[r2 + 64 + n]);
            Cv[j]  = bf2f(dbc[r2 + 80 + n]);
        }
    };
    auto comp = [&](int l0, float* dtv, float* xv, float* Bv, float* Cv, float* zv) {
        #pragma unroll
        for (int j = 0; j < 8; j++) {
            float dtj = dtv[j];
            h = __expf(dtj * Ad) * h + dtj * Bv[j] * xv[j];
            float yv = h * Cv[j];
            yv += __shfl_xor(yv, 8);
            yv += __shfl_xor(yv, 4);
            yv += __shfl_xor(yv, 2);
            yv += __shfl_xor(yv, 1);
            if (n == 0) {
                float zz = zv[j];
                float g  = zz / (1.0f + __expf(-zz));
                float out = (yv + xv[j] * Dpd) * g;
                xp[(rowb + l0 + j) * (long)D_INNER + d] = __float2bfloat16(out);
            }
        }
    };

    ld(0, dt0, x0, B0, C0, z0);
    for (int l0 = 0; l0 < SEQ; l0 += 16) {
        ld(l0 + 8, dt1, x1v, B1, C1, z1);
        comp(l0, dt0, x0, B0, C0, z0);
        if (l0 + 16 < SEQ) ld(l0 + 16, dt0, x0, B0, C0, z0);
        comp(l0 + 8, dt1, x1v, B1, C1, z1);
    }
    state[((long)b * D_INNER + d) * 16 + n] = h;
}

// ---------------------------------------------------------------------------
extern "C" void kernel_launch(void* const* d_in, const int* in_sizes, int n_in,
                              void* d_out, int out_size, void* d_ws, size_t ws_size,
                              hipStream_t stream)
{
    const float* x      = (const float*)d_in[0];
    const float* inw    = (const float*)d_in[1];
    const float* convw  = (const float*)d_in[2];
    const float* convb  = (const float*)d_in[3];
    const float* xprojw = (const float*)d_in[4];
    const float* dtw    = (const float*)d_in[5];
    const float* dtbias = (const float*)d_in[6];
    const float* Alog   = (const float*)d_in[7];
    const float* Dp     = (const float*)d_in[8];
    const float* outw   = (const float*)d_in[9];
    const float* w1     = (const float*)d_in[10];
    const float* b1     = (const float*)d_in[11];
    const float* w2     = (const float*)d_in[12];
    const float* b2     = (const float*)d_in[13];

    float* out0 = (float*)d_out;                     // (2,2048,1024) f32
    float* out1 = out0 + (long)MROWS * D_MODEL;      // (2,2048,16)   f32

    // workspace (bf16): 3 x 8,388,608 + 524,288 + 262,144 elems = 49.5 MiB
    bf16* buf0 = (bf16*)d_ws;                        // xpre -> dt -> hidden (w/ buf1)
    bf16* buf1 = buf0 + (long)MROWS * D_INNER;       // xp -> gated y (in-place)
    bf16* buf2 = buf1 + (long)MROWS * D_INNER;       // z -> x1
    bf16* dbc  = buf2 + (long)MROWS * D_INNER;       // (4096,128), 96 cols used
    bf16* wpad = dbc  + (long)MROWS * 128;           // (128,2048)

    dim3 blk(256);

    pad_xproj<<<dim3(1024), blk, 0, stream>>>(xprojw, wpad);

    // xpre = x @ in_proj_w[0:2048]^T     (4096 x 2048, K=1024)
    gemm_bt<ACT_NONE, false, false, float, float, float, bf16>
        <<<dim3(16, 32), blk, 0, stream>>>(
        x, D_MODEL, inw, buf0, D_INNER, nullptr, (const float*)nullptr, 0, D_MODEL);

    // z = x @ in_proj_w[2048:4096]^T     (4096 x 2048, K=1024)
    gemm_bt<ACT_NONE, false, false, float, float, float, bf16>
        <<<dim3(16, 32), blk, 0, stream>>>(
        x, D_MODEL, inw + (long)D_INNER * D_MODEL, buf2, D_INNER,
        nullptr, (const float*)nullptr, 0, D_MODEL);

    // xp = silu(causal_conv(xpre) + conv_b)
    conv_silu<<<dim3(32768), blk, 0, stream>>>(buf0, convw, convb, buf1);

    // dbc = xp @ x_proj_w^T              (4096 x 128pad, K=2048)
    gemm_bt<ACT_NONE, false, false, bf16, bf16, float, bf16>
        <<<dim3(1, 32), blk, 0, stream>>>(
        buf1, D_INNER, wpad, dbc, 128, nullptr, (const float*)nullptr, 0, D_INNER);

    // dt = softplus(dbc[:, :64] @ dt_proj_w^T + dt_proj_b)   (4096 x 2048, K=64)
    gemm_bt<ACT_SOFTPLUS, true, false, bf16, float, float, bf16>
        <<<dim3(16, 32), blk, 0, stream>>>(
        dbc, 128, dtw, buf0, D_INNER, dtbias, (const float*)nullptr, 0, DT_RANK);

    // scan + gate: gated y in-place into buf1, h_final -> out1 (f32)
    ssm_scan<<<dim3(256), blk, 0, stream>>>(buf0, buf1, dbc, Alog, buf2, Dp, out1);

    // x1 = x + y @ out_proj_w^T          (4096 x 1024, K=2048) -> buf2
    gemm_bt<ACT_NONE, false, true, bf16, float, float, bf16>
        <<<dim3(8, 32), blk, 0, stream>>>(
        buf1, D_INNER, outw, buf2, D_MODEL, nullptr, x, D_MODEL, D_INNER);

    // hidden = gelu(x1 @ w1^T + b1)      (4096 x 4096, K=1024) -> buf0:buf1
    gemm_bt<ACT_GELU, true, false, bf16, float, float, bf16>
        <<<dim3(32, 32), blk, 0, stream>>>(
        buf2, D_MODEL, w1, buf0, D_FFN, b1, (const float*)nullptr, 0, D_MODEL);

    // out0 = x1 + hidden @ w2^T + b2     (4096 x 1024, K=4096) -> d_out (f32)
    gemm_bt<ACT_NONE, true, true, bf16, float, bf16, float>
        <<<dim3(8, 32), blk, 0, stream>>>(
        buf0, D_FFN, w2, out0, D_MODEL, b2, buf2, D_MODEL, D_FFN);
}

// Round 4
// 933.622 us; speedup vs baseline: 1.4811x; 1.4811x over previous
//
#include <hip/hip_runtime.h>
#include <hip/hip_bf16.h>
#include <math.h>

using bf16 = __hip_bfloat16;

typedef __attribute__((ext_vector_type(8))) short short8;
typedef __attribute__((ext_vector_type(4))) float floatx4;

#define D_MODEL 1024
#define D_STATE 16
#define D_FFN   4096
#define D_INNER 2048
#define DT_RANK 64
#define BSZ     2
#define SEQ     2048
#define MROWS   (BSZ*SEQ)   /* 4096 */
#define NCHUNK  16
#define CLEN    (SEQ/NCHUNK)   /* 128 */

static __device__ __forceinline__ float bf2f(bf16 v) { return __bfloat162float(v); }
static __device__ __forceinline__ short f2s(float f) {
    bf16 h = __float2bfloat16(f);
    return *reinterpret_cast<short*>(&h);
}

static __device__ __forceinline__ short8 load8(const bf16* p) {
    return *(const short8*)p;
}
static __device__ __forceinline__ short8 load8(const float* p) {
    float4 a = *(const float4*)p;
    float4 b = *(const float4*)(p + 4);
    short8 r;
    r[0] = f2s(a.x); r[1] = f2s(a.y); r[2] = f2s(a.z); r[3] = f2s(a.w);
    r[4] = f2s(b.x); r[5] = f2s(b.y); r[6] = f2s(b.z); r[7] = f2s(b.w);
    return r;
}
static __device__ __forceinline__ float rd(const bf16* p)  { return bf2f(*p); }
static __device__ __forceinline__ float rd(const float* p) { return *p; }
static __device__ __forceinline__ void  wr(bf16* p, float v)  { *p = __float2bfloat16(v); }
static __device__ __forceinline__ void  wr(float* p, float v) { *p = v; }

// ---------------------------------------------------------------------------
// GEMM: C[M,N] = act(A[M,K] @ W[N,K]^T + bias) (+ resid). f32/bf16 inputs
// converted to bf16 at LDS staging, f32 accum via mfma_f32_16x16x32_bf16.
// ---------------------------------------------------------------------------
#define BM 128
#define BN 128
#define BK 32
#define LDSS 40

enum { ACT_NONE = 0, ACT_GELU = 1, ACT_SOFTPLUS = 2 };

template<int ACT, bool HAS_BIAS, bool HAS_RES,
         typename TA, typename TW, typename TR, typename TC>
__global__ __launch_bounds__(256)
void gemm_bt(const TA* __restrict__ A, int lda,
             const TW* __restrict__ W,
             TC* __restrict__ C, int ldc,
             const float* __restrict__ bias,
             const TR* __restrict__ resid, int ldr,
             int K)
{
    __shared__ __align__(16) bf16 As[BM * LDSS];
    __shared__ __align__(16) bf16 Bs[BN * LDSS];

    const int tid  = threadIdx.x;
    const int lane = tid & 63;
    const int wid  = tid >> 6;
    const int wm   = wid >> 1;
    const int wn   = wid & 1;
    const int quad = lane >> 4;
    const int lrow = lane & 15;

    const long m0 = (long)blockIdx.y * BM;
    const long n0 = (long)blockIdx.x * BN;

    const int c0 = tid, c1 = tid + 256;
    const int r0 = c0 >> 2, o0 = (c0 & 3) * 8;
    const int r1 = c1 >> 2, o1 = (c1 & 3) * 8;

    const TA* Ag0 = A + (m0 + r0) * (long)lda + o0;
    const TA* Ag1 = A + (m0 + r1) * (long)lda + o1;
    const TW* Wg0 = W + (n0 + r0) * (long)K + o0;
    const TW* Wg1 = W + (n0 + r1) * (long)K + o1;

    floatx4 acc[4][4] = {};

    for (int k0 = 0; k0 < K; k0 += BK) {
        short8 a0 = load8(Ag0 + k0);
        short8 a1 = load8(Ag1 + k0);
        short8 b0 = load8(Wg0 + k0);
        short8 b1 = load8(Wg1 + k0);
        __syncthreads();
        *(short8*)(As + r0 * LDSS + o0) = a0;
        *(short8*)(As + r1 * LDSS + o1) = a1;
        *(short8*)(Bs + r0 * LDSS + o0) = b0;
        *(short8*)(Bs + r1 * LDSS + o1) = b1;
        __syncthreads();

        short8 af[4], bfv[4];
        #pragma unroll
        for (int i = 0; i < 4; i++)
            af[i] = *(const short8*)(As + (wm * 64 + i * 16 + lrow) * LDSS + quad * 8);
        #pragma unroll
        for (int j = 0; j < 4; j++)
            bfv[j] = *(const short8*)(Bs + (wn * 64 + j * 16 + lrow) * LDSS + quad * 8);
        #pragma unroll
        for (int i = 0; i < 4; i++)
            #pragma unroll
            for (int j = 0; j < 4; j++)
                acc[i][j] = __builtin_amdgcn_mfma_f32_16x16x32_bf16(af[i], bfv[j], acc[i][j], 0, 0, 0);
    }

    #pragma unroll
    for (int j = 0; j < 4; j++) {
        const long col = n0 + wn * 64 + j * 16 + lrow;
        float bv = HAS_BIAS ? bias[col] : 0.0f;
        #pragma unroll
        for (int i = 0; i < 4; i++) {
            #pragma unroll
            for (int r = 0; r < 4; r++) {
                const long row = m0 + wm * 64 + i * 16 + quad * 4 + r;
                float v = acc[i][j][r] + bv;
                if (ACT == ACT_GELU)     v = 0.5f * v * (1.0f + erff(v * 0.70710678118f));
                if (ACT == ACT_SOFTPLUS) v = (v > 20.0f) ? v : log1pf(__expf(v));
                if (HAS_RES) v += rd(resid + row * (long)ldr + col);
                wr(C + row * (long)ldc + col, v);
            }
        }
    }
}

// ---------------------------------------------------------------------------
// depthwise causal conv (K=3) + bias + silu
// ---------------------------------------------------------------------------
__global__ __launch_bounds__(256)
void conv_silu(const bf16* __restrict__ xpre, const float* __restrict__ cw,
               const float* __restrict__ cb, bf16* __restrict__ xp)
{
    long i = (long)blockIdx.x * 256 + threadIdx.x;
    int  d  = (int)(i & (D_INNER - 1));
    long bl = i >> 11;
    long l  = bl & (SEQ - 1);

    float w0 = cw[d * 3 + 0];
    float w1 = cw[d * 3 + 1];
    float w2 = cw[d * 3 + 2];
    float acc = cb[d] + w2 * bf2f(xpre[i]);
    if (l >= 1) acc += w1 * bf2f(xpre[i - D_INNER]);
    if (l >= 2) acc += w0 * bf2f(xpre[i - 2 * D_INNER]);
    float s = acc / (1.0f + __expf(-acc));
    xp[i] = __float2bfloat16(s);
}

// ---------------------------------------------------------------------------
// pad x_proj_w (96,2048) f32 -> (128,2048) bf16 with zero rows
// ---------------------------------------------------------------------------
__global__ __launch_bounds__(256)
void pad_xproj(const float* __restrict__ src, bf16* __restrict__ dst)
{
    int i = blockIdx.x * 256 + threadIdx.x;
    int row = i >> 11, col = i & 2047;
    dst[i] = (row < 96) ? __float2bfloat16(src[row * 2048 + col])
                        : __float2bfloat16(0.0f);
}

// ---------------------------------------------------------------------------
// Chunked SSM scan. Recurrence h = a*h + b is linear-associative.
// Phase 1: per (b, dgrp, chunk) compute P = exp(Ad*sum(dt)) and Q = local h.
// Phase 2: serial combine over NCHUNK chunks -> exclusive h_in (in-place
//          over Q) + final state.
// Phase 3: rerun chunk from h_in, compute y + gate in-place into xp.
// block = 256 thr = 16 d x 16 n. blockIdx: c | dgrp<<4 | b<<11.
// ---------------------------------------------------------------------------
__global__ __launch_bounds__(256)
void scan_part(const bf16* __restrict__ dt, const bf16* __restrict__ xp,
               const bf16* __restrict__ dbc, const float* __restrict__ Alog,
               float* __restrict__ Pbuf, float* __restrict__ Qbuf)
{
    const int tid  = threadIdx.x;
    const int n    = tid & 15;
    const int dl   = tid >> 4;
    const int c    = blockIdx.x & (NCHUNK - 1);
    const int dgrp = (blockIdx.x >> 4) & 127;
    const int b    = blockIdx.x >> 11;
    const int d    = dgrp * 16 + dl;

    const float Ad = -__expf(Alog[d * 16 + n]);
    float h = 0.0f, sdt = 0.0f;
    const long row0 = (long)b * SEQ + (long)c * CLEN;

    float dtv[2][8], xv[2][8], Bv[2][8];

    auto ld = [&](int l0, int s) {
        #pragma unroll
        for (int j = 0; j < 8; j++) {
            long r = (row0 + l0 + j) * (long)D_INNER + d;
            dtv[s][j] = bf2f(dt[r]);
            xv[s][j]  = bf2f(xp[r]);
            Bv[s][j]  = bf2f(dbc[(row0 + l0 + j) * 128 + 64 + n]);
        }
    };
    auto comp = [&](int s) {
        #pragma unroll
        for (int j = 0; j < 8; j++) {
            float dtj = dtv[s][j];
            float a = __expf(dtj * Ad);
            sdt += dtj;
            h = a * h + dtj * Bv[s][j] * xv[s][j];
        }
    };

    ld(0, 0);
    for (int l0 = 0; l0 < CLEN; l0 += 16) {
        ld(l0 + 8, 1);
        comp(0);
        if (l0 + 16 < CLEN) ld(l0 + 16, 0);
        comp(1);
    }
    const long idx = ((long)(b * NCHUNK + c) * D_INNER + d) * 16 + n;
    Pbuf[idx] = __expf(Ad * sdt);
    Qbuf[idx] = h;
}

__global__ __launch_bounds__(256)
void scan_combine(const float* __restrict__ Pbuf, float* __restrict__ Qbuf,
                  float* __restrict__ state)
{
    long i = (long)blockIdx.x * 256 + threadIdx.x;   // 65536 = (b,d,n)
    int  n = (int)(i & 15);
    int  d = (int)((i >> 4) & (D_INNER - 1));
    int  b = (int)(i >> 15);
    float h = 0.0f;
    #pragma unroll
    for (int c = 0; c < NCHUNK; c++) {
        const long idx = ((long)(b * NCHUNK + c) * D_INNER + d) * 16 + n;
        float P = Pbuf[idx], Q = Qbuf[idx];
        Qbuf[idx] = h;               // exclusive prefix = h_in for chunk c
        h = P * h + Q;
    }
    state[((long)b * D_INNER + d) * 16 + n] = h;
}

__global__ __launch_bounds__(256)
void scan_final(const bf16* __restrict__ dt, bf16* xp,
                const bf16* __restrict__ dbc, const float* __restrict__ Alog,
                const bf16* __restrict__ z, const float* __restrict__ Dp,
                const float* __restrict__ Qbuf)
{
    const int tid  = threadIdx.x;
    const int n    = tid & 15;
    const int dl   = tid >> 4;
    const int c    = blockIdx.x & (NCHUNK - 1);
    const int dgrp = (blockIdx.x >> 4) & 127;
    const int b    = blockIdx.x >> 11;
    const int d    = dgrp * 16 + dl;

    const float Ad  = -__expf(Alog[d * 16 + n]);
    const float Dpd = Dp[d];
    const long row0 = (long)b * SEQ + (long)c * CLEN;

    float h = Qbuf[((long)(b * NCHUNK + c) * D_INNER + d) * 16 + n];

    float dtv[2][8], xv[2][8], Bv[2][8], Cv[2][8], zv[2][8];

    auto ld = [&](int l0, int s) {
        #pragma unroll
        for (int j = 0; j < 8; j++) {
            long r = (row0 + l0 + j) * (long)D_INNER + d;
            dtv[s][j] = bf2f(dt[r]);
            xv[s][j]  = bf2f(xp[r]);
            zv[s][j]  = bf2f(z[r]);
            long r2 = (row0 + l0 + j) * 128;
            Bv[s][j] = bf2f(dbc[r2 + 64 + n]);
            Cv[s][j] = bf2f(dbc[r2 + 80 + n]);
        }
    };
    auto comp = [&](int l0, int s) {
        #pragma unroll
        for (int j = 0; j < 8; j++) {
            float dtj = dtv[s][j];
            h = __expf(dtj * Ad) * h + dtj * Bv[s][j] * xv[s][j];
            float yv = h * Cv[s][j];
            yv += __shfl_xor(yv, 8);
            yv += __shfl_xor(yv, 4);
            yv += __shfl_xor(yv, 2);
            yv += __shfl_xor(yv, 1);
            if (n == 0) {
                float zz = zv[s][j];
                float g  = zz / (1.0f + __expf(-zz));
                float out = (yv + xv[s][j] * Dpd) * g;
                xp[(row0 + l0 + j) * (long)D_INNER + d] = __float2bfloat16(out);
            }
        }
    };

    ld(0, 0);
    for (int l0 = 0; l0 < CLEN; l0 += 16) {
        ld(l0 + 8, 1);
        comp(l0, 0);
        if (l0 + 16 < CLEN) ld(l0 + 16, 0);
        comp(l0 + 8, 1);
    }
}

// ---------------------------------------------------------------------------
extern "C" void kernel_launch(void* const* d_in, const int* in_sizes, int n_in,
                              void* d_out, int out_size, void* d_ws, size_t ws_size,
                              hipStream_t stream)
{
    const float* x      = (const float*)d_in[0];
    const float* inw    = (const float*)d_in[1];
    const float* convw  = (const float*)d_in[2];
    const float* convb  = (const float*)d_in[3];
    const float* xprojw = (const float*)d_in[4];
    const float* dtw    = (const float*)d_in[5];
    const float* dtbias = (const float*)d_in[6];
    const float* Alog   = (const float*)d_in[7];
    const float* Dp     = (const float*)d_in[8];
    const float* outw   = (const float*)d_in[9];
    const float* w1     = (const float*)d_in[10];
    const float* b1     = (const float*)d_in[11];
    const float* w2     = (const float*)d_in[12];
    const float* b2     = (const float*)d_in[13];

    float* out0 = (float*)d_out;                     // (2,2048,1024) f32
    float* out1 = out0 + (long)MROWS * D_MODEL;      // (2,2048,16)   f32

    // workspace: bf16 bufs 49.5 MiB + P/Q f32 8 MiB = 57.5 MiB
    bf16* buf0 = (bf16*)d_ws;                        // xpre -> dt -> hidden (w/ buf1)
    bf16* buf1 = buf0 + (long)MROWS * D_INNER;       // xp -> gated y (in-place)
    bf16* buf2 = buf1 + (long)MROWS * D_INNER;       // z -> x1
    bf16* dbc  = buf2 + (long)MROWS * D_INNER;       // (4096,128), 96 cols used
    bf16* wpad = dbc  + (long)MROWS * 128;           // (128,2048)
    float* Pbuf = (float*)(wpad + 128 * 2048);       // (2*16, 2048, 16) f32
    float* Qbuf = Pbuf + (long)BSZ * NCHUNK * D_INNER * 16;

    dim3 blk(256);

    pad_xproj<<<dim3(1024), blk, 0, stream>>>(xprojw, wpad);

    // xpre = x @ in_proj_w[0:2048]^T     (4096 x 2048, K=1024)
    gemm_bt<ACT_NONE, false, false, float, float, float, bf16>
        <<<dim3(16, 32), blk, 0, stream>>>(
        x, D_MODEL, inw, buf0, D_INNER, nullptr, (const float*)nullptr, 0, D_MODEL);

    // z = x @ in_proj_w[2048:4096]^T     (4096 x 2048, K=1024)
    gemm_bt<ACT_NONE, false, false, float, float, float, bf16>
        <<<dim3(16, 32), blk, 0, stream>>>(
        x, D_MODEL, inw + (long)D_INNER * D_MODEL, buf2, D_INNER,
        nullptr, (const float*)nullptr, 0, D_MODEL);

    // xp = silu(causal_conv(xpre) + conv_b)
    conv_silu<<<dim3(32768), blk, 0, stream>>>(buf0, convw, convb, buf1);

    // dbc = xp @ x_proj_w^T              (4096 x 128pad, K=2048)
    gemm_bt<ACT_NONE, false, false, bf16, bf16, float, bf16>
        <<<dim3(1, 32), blk, 0, stream>>>(
        buf1, D_INNER, wpad, dbc, 128, nullptr, (const float*)nullptr, 0, D_INNER);

    // dt = softplus(dbc[:, :64] @ dt_proj_w^T + dt_proj_b)   (4096 x 2048, K=64)
    gemm_bt<ACT_SOFTPLUS, true, false, bf16, float, float, bf16>
        <<<dim3(16, 32), blk, 0, stream>>>(
        dbc, 128, dtw, buf0, D_INNER, dtbias, (const float*)nullptr, 0, DT_RANK);

    // chunked scan: phase1 -> combine (writes state) -> phase3 (gated y in buf1)
    scan_part<<<dim3(BSZ * 128 * NCHUNK), blk, 0, stream>>>(
        buf0, buf1, dbc, Alog, Pbuf, Qbuf);
    scan_combine<<<dim3(256), blk, 0, stream>>>(Pbuf, Qbuf, out1);
    scan_final<<<dim3(BSZ * 128 * NCHUNK), blk, 0, stream>>>(
        buf0, buf1, dbc, Alog, buf2, Dp, Qbuf);

    // x1 = x + y @ out_proj_w^T          (4096 x 1024, K=2048) -> buf2
    gemm_bt<ACT_NONE, false, true, bf16, float, float, bf16>
        <<<dim3(8, 32), blk, 0, stream>>>(
        buf1, D_INNER, outw, buf2, D_MODEL, nullptr, x, D_MODEL, D_INNER);

    // hidden = gelu(x1 @ w1^T + b1)      (4096 x 4096, K=1024) -> buf0:buf1
    gemm_bt<ACT_GELU, true, false, bf16, float, float, bf16>
        <<<dim3(32, 32), blk, 0, stream>>>(
        buf2, D_MODEL, w1, buf0, D_FFN, b1, (const float*)nullptr, 0, D_MODEL);

    // out0 = x1 + hidden @ w2^T + b2     (4096 x 1024, K=4096) -> d_out (f32)
    gemm_bt<ACT_NONE, true, true, bf16, float, bf16, float>
        <<<dim3(8, 32), blk, 0, stream>>>(
        buf0, D_FFN, w2, out0, D_MODEL, b2, buf2, D_MODEL, D_FFN);
}

// Round 5
// 693.726 us; speedup vs baseline: 1.9932x; 1.3458x over previous
//
#include <hip/hip_runtime.h>
#include <hip/hip_bf16.h>
#include <math.h>

using bf16 = __hip_bfloat16;

typedef __attribute__((ext_vector_type(8))) short short8;
typedef __attribute__((ext_vector_type(4))) short shortx4;
typedef __attribute__((ext_vector_type(4))) float floatx4;

#define D_MODEL 1024
#define D_STATE 16
#define D_FFN   4096
#define D_INNER 2048
#define DT_RANK 64
#define BSZ     2
#define SEQ     2048
#define MROWS   (BSZ*SEQ)   /* 4096 */
#define NCHUNK  16
#define CLEN    (SEQ/NCHUNK)   /* 128 */

static __device__ __forceinline__ float bf2f(bf16 v) { return __bfloat162float(v); }
static __device__ __forceinline__ short f2s(float f) {
    bf16 h = __float2bfloat16(f);
    return *reinterpret_cast<short*>(&h);
}
static __device__ __forceinline__ float sbf(short s) {
    union { short s; bf16 h; } u; u.s = s; return __bfloat162float(u.h);
}

static __device__ __forceinline__ short8 load8(const bf16* p) {
    return *(const short8*)p;
}
static __device__ __forceinline__ short8 load8(const float* p) {
    float4 a = *(const float4*)p;
    float4 b = *(const float4*)(p + 4);
    short8 r;
    r[0] = f2s(a.x); r[1] = f2s(a.y); r[2] = f2s(a.z); r[3] = f2s(a.w);
    r[4] = f2s(b.x); r[5] = f2s(b.y); r[6] = f2s(b.z); r[7] = f2s(b.w);
    return r;
}
static __device__ __forceinline__ float rd(const bf16* p)  { return bf2f(*p); }
static __device__ __forceinline__ float rd(const float* p) { return *p; }
static __device__ __forceinline__ void  wr(bf16* p, float v)  { *p = __float2bfloat16(v); }
static __device__ __forceinline__ void  wr(float* p, float v) { *p = v; }

// ---------------------------------------------------------------------------
// GEMM: C[M,N] = act(A[M,K] @ W[N,K]^T + bias) (+ resid). f32/bf16 inputs
// converted to bf16 at LDS staging, f32 accum via mfma_f32_16x16x32_bf16.
// ---------------------------------------------------------------------------
#define BM 128
#define BN 128
#define BK 32
#define LDSS 40

enum { ACT_NONE = 0, ACT_GELU = 1, ACT_SOFTPLUS = 2 };

template<int ACT, bool HAS_BIAS, bool HAS_RES,
         typename TA, typename TW, typename TR, typename TC>
__global__ __launch_bounds__(256)
void gemm_bt(const TA* __restrict__ A, int lda,
             const TW* __restrict__ W,
             TC* __restrict__ C, int ldc,
             const float* __restrict__ bias,
             const TR* __restrict__ resid, int ldr,
             int K)
{
    __shared__ __align__(16) bf16 As[BM * LDSS];
    __shared__ __align__(16) bf16 Bs[BN * LDSS];

    const int tid  = threadIdx.x;
    const int lane = tid & 63;
    const int wid  = tid >> 6;
    const int wm   = wid >> 1;
    const int wn   = wid & 1;
    const int quad = lane >> 4;
    const int lrow = lane & 15;

    const long m0 = (long)blockIdx.y * BM;
    const long n0 = (long)blockIdx.x * BN;

    const int c0 = tid, c1 = tid + 256;
    const int r0 = c0 >> 2, o0 = (c0 & 3) * 8;
    const int r1 = c1 >> 2, o1 = (c1 & 3) * 8;

    const TA* Ag0 = A + (m0 + r0) * (long)lda + o0;
    const TA* Ag1 = A + (m0 + r1) * (long)lda + o1;
    const TW* Wg0 = W + (n0 + r0) * (long)K + o0;
    const TW* Wg1 = W + (n0 + r1) * (long)K + o1;

    floatx4 acc[4][4] = {};

    for (int k0 = 0; k0 < K; k0 += BK) {
        short8 a0 = load8(Ag0 + k0);
        short8 a1 = load8(Ag1 + k0);
        short8 b0 = load8(Wg0 + k0);
        short8 b1 = load8(Wg1 + k0);
        __syncthreads();
        *(short8*)(As + r0 * LDSS + o0) = a0;
        *(short8*)(As + r1 * LDSS + o1) = a1;
        *(short8*)(Bs + r0 * LDSS + o0) = b0;
        *(short8*)(Bs + r1 * LDSS + o1) = b1;
        __syncthreads();

        short8 af[4], bfv[4];
        #pragma unroll
        for (int i = 0; i < 4; i++)
            af[i] = *(const short8*)(As + (wm * 64 + i * 16 + lrow) * LDSS + quad * 8);
        #pragma unroll
        for (int j = 0; j < 4; j++)
            bfv[j] = *(const short8*)(Bs + (wn * 64 + j * 16 + lrow) * LDSS + quad * 8);
        #pragma unroll
        for (int i = 0; i < 4; i++)
            #pragma unroll
            for (int j = 0; j < 4; j++)
                acc[i][j] = __builtin_amdgcn_mfma_f32_16x16x32_bf16(af[i], bfv[j], acc[i][j], 0, 0, 0);
    }

    #pragma unroll
    for (int j = 0; j < 4; j++) {
        const long col = n0 + wn * 64 + j * 16 + lrow;
        float bv = HAS_BIAS ? bias[col] : 0.0f;
        #pragma unroll
        for (int i = 0; i < 4; i++) {
            #pragma unroll
            for (int r = 0; r < 4; r++) {
                const long row = m0 + wm * 64 + i * 16 + quad * 4 + r;
                float v = acc[i][j][r] + bv;
                if (ACT == ACT_GELU)     v = 0.5f * v * (1.0f + erff(v * 0.70710678118f));
                if (ACT == ACT_SOFTPLUS) v = (v > 20.0f) ? v : log1pf(__expf(v));
                if (HAS_RES) v += rd(resid + row * (long)ldr + col);
                wr(C + row * (long)ldc + col, v);
            }
        }
    }
}

// ---------------------------------------------------------------------------
// depthwise causal conv (K=3) + bias + silu
// ---------------------------------------------------------------------------
__global__ __launch_bounds__(256)
void conv_silu(const bf16* __restrict__ xpre, const float* __restrict__ cw,
               const float* __restrict__ cb, bf16* __restrict__ xp)
{
    long i = (long)blockIdx.x * 256 + threadIdx.x;
    int  d  = (int)(i & (D_INNER - 1));
    long bl = i >> 11;
    long l  = bl & (SEQ - 1);

    float w0 = cw[d * 3 + 0];
    float w1 = cw[d * 3 + 1];
    float w2 = cw[d * 3 + 2];
    float acc = cb[d] + w2 * bf2f(xpre[i]);
    if (l >= 1) acc += w1 * bf2f(xpre[i - D_INNER]);
    if (l >= 2) acc += w0 * bf2f(xpre[i - 2 * D_INNER]);
    float s = acc / (1.0f + __expf(-acc));
    xp[i] = __float2bfloat16(s);
}

// ---------------------------------------------------------------------------
// pad x_proj_w (96,2048) f32 -> (128,2048) bf16 with zero rows
// ---------------------------------------------------------------------------
__global__ __launch_bounds__(256)
void pad_xproj(const float* __restrict__ src, bf16* __restrict__ dst)
{
    int i = blockIdx.x * 256 + threadIdx.x;
    int row = i >> 11, col = i & 2047;
    dst[i] = (row < 96) ? __float2bfloat16(src[row * 2048 + col])
                        : __float2bfloat16(0.0f);
}

// ---------------------------------------------------------------------------
// Chunked SSM scan, LDS-staged.
// Block = 256 thr; compute map: dl = tid>>2 (64 d), nt = tid&3 (4 n-threads,
// each holding h[4] for n = nt*4..nt*4+3). Staging map: sl = tid>>4 (16 rows),
// sq = tid&15. Grid = b(2) x dgrp(32) x chunk(16) = 1024 blocks.
// Per 16-row batch: coalesced global loads -> regs -> packed LDS (double
// buffered, 1 barrier/batch). Per-step LDS reads are immediate-offset b64/b128.
// ---------------------------------------------------------------------------
#define SROWS 16
#define SDB   64
#define SNB   (CLEN/SROWS)   /* 8 */

__global__ __launch_bounds__(256)
void scan_part(const bf16* __restrict__ dt, const bf16* __restrict__ xp,
               const bf16* __restrict__ dbc, const float* __restrict__ Alog,
               float* __restrict__ Pbuf, float* __restrict__ Qbuf)
{
    __shared__ float2 Ap[2][SROWS][SDB];   // (dt, dt*xp)
    __shared__ float  Bp[2][SROWS][16];

    const int tid  = threadIdx.x;
    const int c    = blockIdx.x & (NCHUNK - 1);
    const int dgrp = (blockIdx.x >> 4) & 31;
    const int b    = blockIdx.x >> 9;
    const int d0   = dgrp * SDB;
    const long row0 = (long)b * SEQ + (long)c * CLEN;

    const int sl  = tid >> 4;
    const int sq  = tid & 15;
    const int sd4 = sq * 4;

    const int nt = tid & 3;
    const int dl = tid >> 2;
    const int n0 = nt * 4;
    const int d  = d0 + dl;

    const float4 Av = *(const float4*)(Alog + d * 16 + n0);
    float Ad[4] = { -__expf(Av.x), -__expf(Av.y), -__expf(Av.z), -__expf(Av.w) };

    float rdt[4], rdx[4], rB;
    auto ldb = [&](int bb) {
        long row = row0 + bb * SROWS + sl;
        shortx4 dv = *(const shortx4*)(dt + row * D_INNER + d0 + sd4);
        shortx4 xv = *(const shortx4*)(xp + row * D_INNER + d0 + sd4);
        #pragma unroll
        for (int k = 0; k < 4; k++) {
            float f = sbf(dv[k]);
            rdt[k] = f;
            rdx[k] = f * sbf(xv[k]);
        }
        rB = bf2f(dbc[row * 128 + 64 + sq]);
    };
    auto stb = [&](int bb) {
        int s = bb & 1;
        #pragma unroll
        for (int k = 0; k < 4; k++)
            Ap[s][sl][sd4 + k] = make_float2(rdt[k], rdx[k]);
        Bp[s][sl][sq] = rB;
    };

    float h[4] = {0.f, 0.f, 0.f, 0.f};
    float sdt = 0.f;

    ldb(0); stb(0);
    for (int bb = 0; bb < SNB; bb++) {
        if (bb + 1 < SNB) ldb(bb + 1);
        __syncthreads();
        const int s = bb & 1;
        #pragma unroll
        for (int l = 0; l < SROWS; l++) {
            float2  a  = Ap[s][l][dl];
            floatx4 Bq = *(const floatx4*)&Bp[s][l][n0];
            sdt += a.x;
            #pragma unroll
            for (int k = 0; k < 4; k++)
                h[k] = __expf(a.x * Ad[k]) * h[k] + a.y * Bq[k];
        }
        if (bb + 1 < SNB) stb(bb + 1);
    }

    const long base = ((long)(b * NCHUNK + c) * D_INNER + d) * 16 + n0;
    floatx4 P = { __expf(Ad[0] * sdt), __expf(Ad[1] * sdt),
                  __expf(Ad[2] * sdt), __expf(Ad[3] * sdt) };
    floatx4 Q = { h[0], h[1], h[2], h[3] };
    *(floatx4*)(Pbuf + base) = P;
    *(floatx4*)(Qbuf + base) = Q;
}

__global__ __launch_bounds__(256)
void scan_combine(const float* __restrict__ Pbuf, float* __restrict__ Qbuf,
                  float* __restrict__ state)
{
    long i = (long)blockIdx.x * 256 + threadIdx.x;   // 65536 = (b,d,n)
    int  n = (int)(i & 15);
    int  d = (int)((i >> 4) & (D_INNER - 1));
    int  b = (int)(i >> 15);
    float h = 0.0f;
    #pragma unroll
    for (int c = 0; c < NCHUNK; c++) {
        const long idx = ((long)(b * NCHUNK + c) * D_INNER + d) * 16 + n;
        float P = Pbuf[idx], Q = Qbuf[idx];
        Qbuf[idx] = h;               // exclusive prefix = h_in for chunk c
        h = P * h + Q;
    }
    state[((long)b * D_INNER + d) * 16 + n] = h;
}

__global__ __launch_bounds__(256)
void scan_final(const bf16* __restrict__ dt, bf16* __restrict__ xp,
                const bf16* __restrict__ dbc, const float* __restrict__ Alog,
                const bf16* __restrict__ z, const float* __restrict__ Dp,
                const float* __restrict__ Qbuf)
{
    __shared__ float2 Ap [2][SROWS][SDB];   // (dt, dt*xp)
    __shared__ float2 BCp[2][SROWS][16];    // (B, C)
    __shared__ float2 GWp[2][SROWS][SDB];   // (g=silu(z), w=xp*Dp*g)

    const int tid  = threadIdx.x;
    const int c    = blockIdx.x & (NCHUNK - 1);
    const int dgrp = (blockIdx.x >> 4) & 31;
    const int b    = blockIdx.x >> 9;
    const int d0   = dgrp * SDB;
    const long row0 = (long)b * SEQ + (long)c * CLEN;

    const int sl  = tid >> 4;
    const int sq  = tid & 15;
    const int sd4 = sq * 4;

    const int nt = tid & 3;
    const int dl = tid >> 2;
    const int n0 = nt * 4;
    const int d  = d0 + dl;

    const float4 Av = *(const float4*)(Alog + d * 16 + n0);
    float Ad[4] = { -__expf(Av.x), -__expf(Av.y), -__expf(Av.z), -__expf(Av.w) };
    const float4 Dv = *(const float4*)(Dp + d0 + sd4);
    const float Dk[4] = { Dv.x, Dv.y, Dv.z, Dv.w };

    float rdt[4], rdx[4], rg[4], rw[4], rB, rC;
    auto ldb = [&](int bb) {
        long row = row0 + bb * SROWS + sl;
        shortx4 dv = *(const shortx4*)(dt + row * D_INNER + d0 + sd4);
        shortx4 xv = *(const shortx4*)(xp + row * D_INNER + d0 + sd4);
        shortx4 zv = *(const shortx4*)(z  + row * D_INNER + d0 + sd4);
        #pragma unroll
        for (int k = 0; k < 4; k++) {
            float f  = sbf(dv[k]);
            float xf = sbf(xv[k]);
            float zf = sbf(zv[k]);
            float g  = zf / (1.0f + __expf(-zf));
            rdt[k] = f;
            rdx[k] = f * xf;
            rg[k]  = g;
            rw[k]  = xf * Dk[k] * g;
        }
        rB = bf2f(dbc[row * 128 + 64 + sq]);
        rC = bf2f(dbc[row * 128 + 80 + sq]);
    };
    auto stb = [&](int bb) {
        int s = bb & 1;
        #pragma unroll
        for (int k = 0; k < 4; k++) {
            Ap [s][sl][sd4 + k] = make_float2(rdt[k], rdx[k]);
            GWp[s][sl][sd4 + k] = make_float2(rg[k], rw[k]);
        }
        BCp[s][sl][sq] = make_float2(rB, rC);
    };

    float h[4];
    {
        const long base = ((long)(b * NCHUNK + c) * D_INNER + d) * 16 + n0;
        floatx4 q = *(const floatx4*)(Qbuf + base);
        h[0] = q[0]; h[1] = q[1]; h[2] = q[2]; h[3] = q[3];
    }

    ldb(0); stb(0);
    for (int bb = 0; bb < SNB; bb++) {
        if (bb + 1 < SNB) ldb(bb + 1);
        __syncthreads();
        const int s = bb & 1;
        #pragma unroll
        for (int l = 0; l < SROWS; l++) {
            float2  a   = Ap[s][l][dl];
            floatx4 bc0 = *(const floatx4*)&BCp[s][l][n0];      // B0,C0,B1,C1
            floatx4 bc1 = *(const floatx4*)&BCp[s][l][n0 + 2];  // B2,C2,B3,C3
            float yv;
            h[0] = __expf(a.x * Ad[0]) * h[0] + a.y * bc0[0];
            yv   = h[0] * bc0[1];
            h[1] = __expf(a.x * Ad[1]) * h[1] + a.y * bc0[2];
            yv  += h[1] * bc0[3];
            h[2] = __expf(a.x * Ad[2]) * h[2] + a.y * bc1[0];
            yv  += h[2] * bc1[1];
            h[3] = __expf(a.x * Ad[3]) * h[3] + a.y * bc1[2];
            yv  += h[3] * bc1[3];
            yv += __shfl_xor(yv, 1);
            yv += __shfl_xor(yv, 2);
            if (nt == 0) {
                float2 gw = GWp[s][l][dl];
                float out = yv * gw.x + gw.y;
                xp[(row0 + bb * SROWS + l) * (long)D_INNER + d0 + dl] =
                    __float2bfloat16(out);
            }
        }
        if (bb + 1 < SNB) stb(bb + 1);
    }
}

// ---------------------------------------------------------------------------
extern "C" void kernel_launch(void* const* d_in, const int* in_sizes, int n_in,
                              void* d_out, int out_size, void* d_ws, size_t ws_size,
                              hipStream_t stream)
{
    const float* x      = (const float*)d_in[0];
    const float* inw    = (const float*)d_in[1];
    const float* convw  = (const float*)d_in[2];
    const float* convb  = (const float*)d_in[3];
    const float* xprojw = (const float*)d_in[4];
    const float* dtw    = (const float*)d_in[5];
    const float* dtbias = (const float*)d_in[6];
    const float* Alog   = (const float*)d_in[7];
    const float* Dp     = (const float*)d_in[8];
    const float* outw   = (const float*)d_in[9];
    const float* w1     = (const float*)d_in[10];
    const float* b1     = (const float*)d_in[11];
    const float* w2     = (const float*)d_in[12];
    const float* b2     = (const float*)d_in[13];

    float* out0 = (float*)d_out;                     // (2,2048,1024) f32
    float* out1 = out0 + (long)MROWS * D_MODEL;      // (2,2048,16)   f32

    // workspace: bf16 bufs 49.5 MiB + P/Q f32 8 MiB = 57.5 MiB
    bf16* buf0 = (bf16*)d_ws;                        // xpre -> dt -> hidden (w/ buf1)
    bf16* buf1 = buf0 + (long)MROWS * D_INNER;       // xp -> gated y (in-place)
    bf16* buf2 = buf1 + (long)MROWS * D_INNER;       // z -> x1
    bf16* dbc  = buf2 + (long)MROWS * D_INNER;       // (4096,128), 96 cols used
    bf16* wpad = dbc  + (long)MROWS * 128;           // (128,2048)
    float* Pbuf = (float*)(wpad + 128 * 2048);       // (2*16, 2048, 16) f32
    float* Qbuf = Pbuf + (long)BSZ * NCHUNK * D_INNER * 16;

    dim3 blk(256);

    pad_xproj<<<dim3(1024), blk, 0, stream>>>(xprojw, wpad);

    // xpre = x @ in_proj_w[0:2048]^T     (4096 x 2048, K=1024)
    gemm_bt<ACT_NONE, false, false, float, float, float, bf16>
        <<<dim3(16, 32), blk, 0, stream>>>(
        x, D_MODEL, inw, buf0, D_INNER, nullptr, (const float*)nullptr, 0, D_MODEL);

    // z = x @ in_proj_w[2048:4096]^T     (4096 x 2048, K=1024)
    gemm_bt<ACT_NONE, false, false, float, float, float, bf16>
        <<<dim3(16, 32), blk, 0, stream>>>(
        x, D_MODEL, inw + (long)D_INNER * D_MODEL, buf2, D_INNER,
        nullptr, (const float*)nullptr, 0, D_MODEL);

    // xp = silu(causal_conv(xpre) + conv_b)
    conv_silu<<<dim3(32768), blk, 0, stream>>>(buf0, convw, convb, buf1);

    // dbc = xp @ x_proj_w^T              (4096 x 128pad, K=2048)
    gemm_bt<ACT_NONE, false, false, bf16, bf16, float, bf16>
        <<<dim3(1, 32), blk, 0, stream>>>(
        buf1, D_INNER, wpad, dbc, 128, nullptr, (const float*)nullptr, 0, D_INNER);

    // dt = softplus(dbc[:, :64] @ dt_proj_w^T + dt_proj_b)   (4096 x 2048, K=64)
    gemm_bt<ACT_SOFTPLUS, true, false, bf16, float, float, bf16>
        <<<dim3(16, 32), blk, 0, stream>>>(
        dbc, 128, dtw, buf0, D_INNER, dtbias, (const float*)nullptr, 0, DT_RANK);

    // chunked scan: phase1 -> combine (writes state) -> phase3 (gated y in buf1)
    scan_part<<<dim3(BSZ * NCHUNK * (D_INNER / SDB)), blk, 0, stream>>>(
        buf0, buf1, dbc, Alog, Pbuf, Qbuf);
    scan_combine<<<dim3(256), blk, 0, stream>>>(Pbuf, Qbuf, out1);
    scan_final<<<dim3(BSZ * NCHUNK * (D_INNER / SDB)), blk, 0, stream>>>(
        buf0, buf1, dbc, Alog, buf2, Dp, Qbuf);

    // x1 = x + y @ out_proj_w^T          (4096 x 1024, K=2048) -> buf2
    gemm_bt<ACT_NONE, false, true, bf16, float, float, bf16>
        <<<dim3(8, 32), blk, 0, stream>>>(
        buf1, D_INNER, outw, buf2, D_MODEL, nullptr, x, D_MODEL, D_INNER);

    // hidden = gelu(x1 @ w1^T + b1)      (4096 x 4096, K=1024) -> buf0:buf1
    gemm_bt<ACT_GELU, true, false, bf16, float, float, bf16>
        <<<dim3(32, 32), blk, 0, stream>>>(
        buf2, D_MODEL, w1, buf0, D_FFN, b1, (const float*)nullptr, 0, D_MODEL);

    // out0 = x1 + hidden @ w2^T + b2     (4096 x 1024, K=4096) -> d_out (f32)
    gemm_bt<ACT_NONE, true, true, bf16, float, bf16, float>
        <<<dim3(8, 32), blk, 0, stream>>>(
        buf0, D_FFN, w2, out0, D_MODEL, b2, buf2, D_MODEL, D_FFN);
}

// Round 6
// 601.448 us; speedup vs baseline: 2.2990x; 1.1534x over previous
//
#include <hip/hip_runtime.h>
#include <hip/hip_bf16.h>
#include <math.h>

using bf16 = __hip_bfloat16;

typedef __attribute__((ext_vector_type(8))) short short8;
typedef __attribute__((ext_vector_type(4))) short shortx4;
typedef __attribute__((ext_vector_type(4))) float floatx4;

#define D_MODEL 1024
#define D_STATE 16
#define D_FFN   4096
#define D_INNER 2048
#define DT_RANK 64
#define BSZ     2
#define SEQ     2048
#define MROWS   (BSZ*SEQ)   /* 4096 */
#define NCHUNK  16
#define CLEN    (SEQ/NCHUNK)   /* 128 */

static __device__ __forceinline__ float bf2f(bf16 v) { return __bfloat162float(v); }
static __device__ __forceinline__ short f2s(float f) {
    bf16 h = __float2bfloat16(f);
    return *reinterpret_cast<short*>(&h);
}
static __device__ __forceinline__ float sbf(short s) {
    union { short s; bf16 h; } u; u.s = s; return __bfloat162float(u.h);
}
static __device__ __forceinline__ float rd(const bf16* p)  { return bf2f(*p); }
static __device__ __forceinline__ float rd(const float* p) { return *p; }
static __device__ __forceinline__ void  wr(bf16* p, float v)  { *p = __float2bfloat16(v); }
static __device__ __forceinline__ void  wr(float* p, float v) { *p = v; }

// async global->LDS, 16B per lane, wave-uniform LDS base (HW: base + lane*16)
static __device__ __forceinline__ void gload16(const bf16* g, bf16* l) {
    __builtin_amdgcn_global_load_lds(
        (const __attribute__((address_space(1))) void*)g,
        (__attribute__((address_space(3))) void*)l, 16, 0, 0);
}

// ---------------------------------------------------------------------------
// GEMM: C[M,N] = act(A[M,K] @ W[N,K]^T + bias) (+ resid). bf16 in, f32 accum.
// m97 structure: 128x128 tile, BK=32, unpadded LDS (global_load_lds width=16),
// 2-barrier K-loop, 4 waves x (4x4) mfma_f32_16x16x32_bf16.
// ---------------------------------------------------------------------------
#define BK 32

enum { ACT_NONE = 0, ACT_GELU = 1, ACT_SOFTPLUS = 2 };

template<int ACT, bool HAS_BIAS, bool HAS_RES, typename TR, typename TC>
__global__ __launch_bounds__(256)
void gemm_bt(const bf16* __restrict__ A, int lda,
             const bf16* __restrict__ W,
             TC* __restrict__ C, int ldc,
             const float* __restrict__ bias,
             const TR* __restrict__ resid, int ldr,
             int K)
{
    __shared__ __align__(16) bf16 As[128 * BK];
    __shared__ __align__(16) bf16 Bs[128 * BK];

    const int tid  = threadIdx.x;
    const int lane = tid & 63;
    const int wid  = tid >> 6;
    const int wm   = wid >> 1;
    const int wn   = wid & 1;
    const int quad = lane >> 4;
    const int lrow = lane & 15;

    const long m0 = (long)blockIdx.y * 128;
    const long n0 = (long)blockIdx.x * 128;

    // async staging: 8 instrs/tile (16 rows each); wave w issues q = 2w, 2w+1
    const int rA = lane >> 2;          // 0..15 row within 16-row group
    const int kA = (lane & 3) * 8;     // 0,8,16,24
    const int q0 = wid * 2, q1 = wid * 2 + 1;

    const bf16* Ag0 = A + (m0 + q0 * 16 + rA) * (long)lda + kA;
    const bf16* Ag1 = A + (m0 + q1 * 16 + rA) * (long)lda + kA;
    const bf16* Wg0 = W + (n0 + q0 * 16 + rA) * (long)K + kA;
    const bf16* Wg1 = W + (n0 + q1 * 16 + rA) * (long)K + kA;
    bf16* AsL0 = As + q0 * 512;   // 16 rows * 32 elems
    bf16* AsL1 = As + q1 * 512;
    bf16* BsL0 = Bs + q0 * 512;
    bf16* BsL1 = Bs + q1 * 512;

    floatx4 acc[4][4] = {};

    for (int k0 = 0; k0 < K; k0 += BK) {
        __syncthreads();                 // LDS safe to overwrite
        gload16(Ag0 + k0, AsL0);
        gload16(Ag1 + k0, AsL1);
        gload16(Wg0 + k0, BsL0);
        gload16(Wg1 + k0, BsL1);
        __syncthreads();                 // vmcnt(0) drain + barrier

        short8 af[4], bfv[4];
        #pragma unroll
        for (int i = 0; i < 4; i++)
            af[i] = *(const short8*)(As + (wm * 64 + i * 16 + lrow) * BK + quad * 8);
        #pragma unroll
        for (int j = 0; j < 4; j++)
            bfv[j] = *(const short8*)(Bs + (wn * 64 + j * 16 + lrow) * BK + quad * 8);
        #pragma unroll
        for (int i = 0; i < 4; i++)
            #pragma unroll
            for (int j = 0; j < 4; j++)
                acc[i][j] = __builtin_amdgcn_mfma_f32_16x16x32_bf16(af[i], bfv[j], acc[i][j], 0, 0, 0);
    }

    // epilogue: D row = quad*4 + r, col = lrow (verified m89 C/D layout)
    #pragma unroll
    for (int j = 0; j < 4; j++) {
        const long col = n0 + wn * 64 + j * 16 + lrow;
        float bv = HAS_BIAS ? bias[col] : 0.0f;
        #pragma unroll
        for (int i = 0; i < 4; i++) {
            #pragma unroll
            for (int r = 0; r < 4; r++) {
                const long row = m0 + wm * 64 + i * 16 + quad * 4 + r;
                float v = acc[i][j][r] + bv;
                if (ACT == ACT_GELU)     v = 0.5f * v * (1.0f + erff(v * 0.70710678118f));
                if (ACT == ACT_SOFTPLUS) v = (v > 20.0f) ? v : log1pf(__expf(v));
                if (HAS_RES) v += rd(resid + row * (long)ldr + col);
                wr(C + row * (long)ldc + col, v);
            }
        }
    }
}

// ---------------------------------------------------------------------------
// f32 -> bf16 convert, 8 elems/thread (n8 = n/8, must be multiple of 256)
// ---------------------------------------------------------------------------
__global__ __launch_bounds__(256)
void cvt_bf16(const float* __restrict__ src, bf16* __restrict__ dst)
{
    long i = (long)blockIdx.x * 256 + threadIdx.x;
    float4 a = *((const float4*)src + i * 2);
    float4 b = *((const float4*)src + i * 2 + 1);
    short8 r;
    r[0] = f2s(a.x); r[1] = f2s(a.y); r[2] = f2s(a.z); r[3] = f2s(a.w);
    r[4] = f2s(b.x); r[5] = f2s(b.y); r[6] = f2s(b.z); r[7] = f2s(b.w);
    *(short8*)(dst + i * 8) = r;
}

// ---------------------------------------------------------------------------
// depthwise causal conv (K=3) + bias + silu
// ---------------------------------------------------------------------------
__global__ __launch_bounds__(256)
void conv_silu(const bf16* __restrict__ xpre, const float* __restrict__ cw,
               const float* __restrict__ cb, bf16* __restrict__ xp)
{
    long i = (long)blockIdx.x * 256 + threadIdx.x;
    int  d  = (int)(i & (D_INNER - 1));
    long bl = i >> 11;
    long l  = bl & (SEQ - 1);

    float w0 = cw[d * 3 + 0];
    float w1 = cw[d * 3 + 1];
    float w2 = cw[d * 3 + 2];
    float acc = cb[d] + w2 * bf2f(xpre[i]);
    if (l >= 1) acc += w1 * bf2f(xpre[i - D_INNER]);
    if (l >= 2) acc += w0 * bf2f(xpre[i - 2 * D_INNER]);
    float s = acc / (1.0f + __expf(-acc));
    xp[i] = __float2bfloat16(s);
}

// ---------------------------------------------------------------------------
// pad x_proj_w (96,2048) f32 -> (128,2048) bf16 with zero rows
// ---------------------------------------------------------------------------
__global__ __launch_bounds__(256)
void pad_xproj(const float* __restrict__ src, bf16* __restrict__ dst)
{
    int i = blockIdx.x * 256 + threadIdx.x;
    int row = i >> 11, col = i & 2047;
    dst[i] = (row < 96) ? __float2bfloat16(src[row * 2048 + col])
                        : __float2bfloat16(0.0f);
}

// ---------------------------------------------------------------------------
// Chunked SSM scan (unchanged from round 5 — verified)
// ---------------------------------------------------------------------------
#define SROWS 16
#define SDB   64
#define SNB   (CLEN/SROWS)   /* 8 */

__global__ __launch_bounds__(256)
void scan_part(const bf16* __restrict__ dt, const bf16* __restrict__ xp,
               const bf16* __restrict__ dbc, const float* __restrict__ Alog,
               float* __restrict__ Pbuf, float* __restrict__ Qbuf)
{
    __shared__ float2 Ap[2][SROWS][SDB];   // (dt, dt*xp)
    __shared__ float  Bp[2][SROWS][16];

    const int tid  = threadIdx.x;
    const int c    = blockIdx.x & (NCHUNK - 1);
    const int dgrp = (blockIdx.x >> 4) & 31;
    const int b    = blockIdx.x >> 9;
    const int d0   = dgrp * SDB;
    const long row0 = (long)b * SEQ + (long)c * CLEN;

    const int sl  = tid >> 4;
    const int sq  = tid & 15;
    const int sd4 = sq * 4;

    const int nt = tid & 3;
    const int dl = tid >> 2;
    const int n0 = nt * 4;
    const int d  = d0 + dl;

    const float4 Av = *(const float4*)(Alog + d * 16 + n0);
    float Ad[4] = { -__expf(Av.x), -__expf(Av.y), -__expf(Av.z), -__expf(Av.w) };

    float rdt[4], rdx[4], rB;
    auto ldb = [&](int bb) {
        long row = row0 + bb * SROWS + sl;
        shortx4 dv = *(const shortx4*)(dt + row * D_INNER + d0 + sd4);
        shortx4 xv = *(const shortx4*)(xp + row * D_INNER + d0 + sd4);
        #pragma unroll
        for (int k = 0; k < 4; k++) {
            float f = sbf(dv[k]);
            rdt[k] = f;
            rdx[k] = f * sbf(xv[k]);
        }
        rB = bf2f(dbc[row * 128 + 64 + sq]);
    };
    auto stb = [&](int bb) {
        int s = bb & 1;
        #pragma unroll
        for (int k = 0; k < 4; k++)
            Ap[s][sl][sd4 + k] = make_float2(rdt[k], rdx[k]);
        Bp[s][sl][sq] = rB;
    };

    float h[4] = {0.f, 0.f, 0.f, 0.f};
    float sdt = 0.f;

    ldb(0); stb(0);
    for (int bb = 0; bb < SNB; bb++) {
        if (bb + 1 < SNB) ldb(bb + 1);
        __syncthreads();
        const int s = bb & 1;
        #pragma unroll
        for (int l = 0; l < SROWS; l++) {
            float2  a  = Ap[s][l][dl];
            floatx4 Bq = *(const floatx4*)&Bp[s][l][n0];
            sdt += a.x;
            #pragma unroll
            for (int k = 0; k < 4; k++)
                h[k] = __expf(a.x * Ad[k]) * h[k] + a.y * Bq[k];
        }
        if (bb + 1 < SNB) stb(bb + 1);
    }

    const long base = ((long)(b * NCHUNK + c) * D_INNER + d) * 16 + n0;
    floatx4 P = { __expf(Ad[0] * sdt), __expf(Ad[1] * sdt),
                  __expf(Ad[2] * sdt), __expf(Ad[3] * sdt) };
    floatx4 Q = { h[0], h[1], h[2], h[3] };
    *(floatx4*)(Pbuf + base) = P;
    *(floatx4*)(Qbuf + base) = Q;
}

__global__ __launch_bounds__(256)
void scan_combine(const float* __restrict__ Pbuf, float* __restrict__ Qbuf,
                  float* __restrict__ state)
{
    long i = (long)blockIdx.x * 256 + threadIdx.x;   // 65536 = (b,d,n)
    int  n = (int)(i & 15);
    int  d = (int)((i >> 4) & (D_INNER - 1));
    int  b = (int)(i >> 15);
    float h = 0.0f;
    #pragma unroll
    for (int c = 0; c < NCHUNK; c++) {
        const long idx = ((long)(b * NCHUNK + c) * D_INNER + d) * 16 + n;
        float P = Pbuf[idx], Q = Qbuf[idx];
        Qbuf[idx] = h;               // exclusive prefix = h_in for chunk c
        h = P * h + Q;
    }
    state[((long)b * D_INNER + d) * 16 + n] = h;
}

__global__ __launch_bounds__(256)
void scan_final(const bf16* __restrict__ dt, bf16* __restrict__ xp,
                const bf16* __restrict__ dbc, const float* __restrict__ Alog,
                const bf16* __restrict__ z, const float* __restrict__ Dp,
                const float* __restrict__ Qbuf)
{
    __shared__ float2 Ap [2][SROWS][SDB];   // (dt, dt*xp)
    __shared__ float2 BCp[2][SROWS][16];    // (B, C)
    __shared__ float2 GWp[2][SROWS][SDB];   // (g=silu(z), w=xp*Dp*g)

    const int tid  = threadIdx.x;
    const int c    = blockIdx.x & (NCHUNK - 1);
    const int dgrp = (blockIdx.x >> 4) & 31;
    const int b    = blockIdx.x >> 9;
    const int d0   = dgrp * SDB;
    const long row0 = (long)b * SEQ + (long)c * CLEN;

    const int sl  = tid >> 4;
    const int sq  = tid & 15;
    const int sd4 = sq * 4;

    const int nt = tid & 3;
    const int dl = tid >> 2;
    const int n0 = nt * 4;
    const int d  = d0 + dl;

    const float4 Av = *(const float4*)(Alog + d * 16 + n0);
    float Ad[4] = { -__expf(Av.x), -__expf(Av.y), -__expf(Av.z), -__expf(Av.w) };
    const float4 Dv = *(const float4*)(Dp + d0 + sd4);
    const float Dk[4] = { Dv.x, Dv.y, Dv.z, Dv.w };

    float rdt[4], rdx[4], rg[4], rw[4], rB, rC;
    auto ldb = [&](int bb) {
        long row = row0 + bb * SROWS + sl;
        shortx4 dv = *(const shortx4*)(dt + row * D_INNER + d0 + sd4);
        shortx4 xv = *(const shortx4*)(xp + row * D_INNER + d0 + sd4);
        shortx4 zv = *(const shortx4*)(z  + row * D_INNER + d0 + sd4);
        #pragma unroll
        for (int k = 0; k < 4; k++) {
            float f  = sbf(dv[k]);
            float xf = sbf(xv[k]);
            float zf = sbf(zv[k]);
            float g  = zf / (1.0f + __expf(-zf));
            rdt[k] = f;
            rdx[k] = f * xf;
            rg[k]  = g;
            rw[k]  = xf * Dk[k] * g;
        }
        rB = bf2f(dbc[row * 128 + 64 + sq]);
        rC = bf2f(dbc[row * 128 + 80 + sq]);
    };
    auto stb = [&](int bb) {
        int s = bb & 1;
        #pragma unroll
        for (int k = 0; k < 4; k++) {
            Ap [s][sl][sd4 + k] = make_float2(rdt[k], rdx[k]);
            GWp[s][sl][sd4 + k] = make_float2(rg[k], rw[k]);
        }
        BCp[s][sl][sq] = make_float2(rB, rC);
    };

    float h[4];
    {
        const long base = ((long)(b * NCHUNK + c) * D_INNER + d) * 16 + n0;
        floatx4 q = *(const floatx4*)(Qbuf + base);
        h[0] = q[0]; h[1] = q[1]; h[2] = q[2]; h[3] = q[3];
    }

    ldb(0); stb(0);
    for (int bb = 0; bb < SNB; bb++) {
        if (bb + 1 < SNB) ldb(bb + 1);
        __syncthreads();
        const int s = bb & 1;
        #pragma unroll
        for (int l = 0; l < SROWS; l++) {
            float2  a   = Ap[s][l][dl];
            floatx4 bc0 = *(const floatx4*)&BCp[s][l][n0];      // B0,C0,B1,C1
            floatx4 bc1 = *(const floatx4*)&BCp[s][l][n0 + 2];  // B2,C2,B3,C3
            float yv;
            h[0] = __expf(a.x * Ad[0]) * h[0] + a.y * bc0[0];
            yv   = h[0] * bc0[1];
            h[1] = __expf(a.x * Ad[1]) * h[1] + a.y * bc0[2];
            yv  += h[1] * bc0[3];
            h[2] = __expf(a.x * Ad[2]) * h[2] + a.y * bc1[0];
            yv  += h[2] * bc1[1];
            h[3] = __expf(a.x * Ad[3]) * h[3] + a.y * bc1[2];
            yv  += h[3] * bc1[3];
            yv += __shfl_xor(yv, 1);
            yv += __shfl_xor(yv, 2);
            if (nt == 0) {
                float2 gw = GWp[s][l][dl];
                float out = yv * gw.x + gw.y;
                xp[(row0 + bb * SROWS + l) * (long)D_INNER + d0 + dl] =
                    __float2bfloat16(out);
            }
        }
        if (bb + 1 < SNB) stb(bb + 1);
    }
}

// ---------------------------------------------------------------------------
extern "C" void kernel_launch(void* const* d_in, const int* in_sizes, int n_in,
                              void* d_out, int out_size, void* d_ws, size_t ws_size,
                              hipStream_t stream)
{
    const float* x      = (const float*)d_in[0];
    const float* inw    = (const float*)d_in[1];
    const float* convw  = (const float*)d_in[2];
    const float* convb  = (const float*)d_in[3];
    const float* xprojw = (const float*)d_in[4];
    const float* dtw    = (const float*)d_in[5];
    const float* dtbias = (const float*)d_in[6];
    const float* Alog   = (const float*)d_in[7];
    const float* Dp     = (const float*)d_in[8];
    const float* outw   = (const float*)d_in[9];
    const float* w1     = (const float*)d_in[10];
    const float* b1     = (const float*)d_in[11];
    const float* w2     = (const float*)d_in[12];
    const float* b2     = (const float*)d_in[13];

    float* out0 = (float*)d_out;                     // (2,2048,1024) f32
    float* out1 = out0 + (long)MROWS * D_MODEL;      // (2,2048,16)   f32 @ +16MB

    // ws (57.5 MiB, proven size): 3 act bufs + dbc + wpad + rotating weight slot
    bf16* buf0 = (bf16*)d_ws;                        // xpre -> dt -> hidden lo
    bf16* buf1 = buf0 + (long)MROWS * D_INNER;       // xp -> gated y (in-place) -> hidden hi
    bf16* buf2 = buf1 + (long)MROWS * D_INNER;       // z -> x1
    bf16* dbc  = buf2 + (long)MROWS * D_INNER;       // (4096,128), 96 cols used
    bf16* wpad = dbc  + (long)MROWS * 128;           // (128,2048)
    bf16* W8   = wpad + 128 * 2048;                  // 8 MiB rotating: inw->dtw->outw->w1->w2

    // d_out[0:16MB] as scratch (dead before final GEMM writes out0):
    float* Pbuf = (float*)d_out;                     // 4 MiB  (scan)
    float* Qbuf = Pbuf + (long)BSZ * NCHUNK * D_INNER * 16;   // 4 MiB
    bf16*  xbf  = (bf16*)((char*)d_out + 8 * 1024 * 1024);    // 8 MiB (in_proj A)

    dim3 blk(256);

    // x, in_proj_w -> bf16
    cvt_bf16<<<dim3(2048), blk, 0, stream>>>(x, xbf);        // 4096*1024
    cvt_bf16<<<dim3(2048), blk, 0, stream>>>(inw, W8);       // 4096*1024
    pad_xproj<<<dim3(1024), blk, 0, stream>>>(xprojw, wpad);

    // xpre = x @ in_proj_w[0:2048]^T     (4096 x 2048, K=1024)
    gemm_bt<ACT_NONE, false, false, float, bf16>
        <<<dim3(16, 32), blk, 0, stream>>>(
        xbf, D_MODEL, W8, buf0, D_INNER, nullptr, (const float*)nullptr, 0, D_MODEL);

    // z = x @ in_proj_w[2048:4096]^T     (4096 x 2048, K=1024)
    gemm_bt<ACT_NONE, false, false, float, bf16>
        <<<dim3(16, 32), blk, 0, stream>>>(
        xbf, D_MODEL, W8 + (long)D_INNER * D_MODEL, buf2, D_INNER,
        nullptr, (const float*)nullptr, 0, D_MODEL);

    // xp = silu(causal_conv(xpre) + conv_b)
    conv_silu<<<dim3(32768), blk, 0, stream>>>(buf0, convw, convb, buf1);

    // dbc = xp @ x_proj_w^T              (4096 x 128pad, K=2048)
    gemm_bt<ACT_NONE, false, false, float, bf16>
        <<<dim3(1, 32), blk, 0, stream>>>(
        buf1, D_INNER, wpad, dbc, 128, nullptr, (const float*)nullptr, 0, D_INNER);

    // dt = softplus(dbc[:, :64] @ dt_proj_w^T + dt_proj_b)   (4096 x 2048, K=64)
    cvt_bf16<<<dim3(64), blk, 0, stream>>>(dtw, W8);         // 2048*64
    gemm_bt<ACT_SOFTPLUS, true, false, float, bf16>
        <<<dim3(16, 32), blk, 0, stream>>>(
        dbc, 128, W8, buf0, D_INNER, dtbias, (const float*)nullptr, 0, DT_RANK);

    // chunked scan: phase1 -> combine (writes state) -> phase3 (gated y in buf1)
    scan_part<<<dim3(BSZ * NCHUNK * (D_INNER / SDB)), blk, 0, stream>>>(
        buf0, buf1, dbc, Alog, Pbuf, Qbuf);
    scan_combine<<<dim3(256), blk, 0, stream>>>(Pbuf, Qbuf, out1);
    scan_final<<<dim3(BSZ * NCHUNK * (D_INNER / SDB)), blk, 0, stream>>>(
        buf0, buf1, dbc, Alog, buf2, Dp, Qbuf);

    // x1 = x + y @ out_proj_w^T          (4096 x 1024, K=2048) -> buf2
    cvt_bf16<<<dim3(1024), blk, 0, stream>>>(outw, W8);      // 1024*2048
    gemm_bt<ACT_NONE, false, true, float, bf16>
        <<<dim3(8, 32), blk, 0, stream>>>(
        buf1, D_INNER, W8, buf2, D_MODEL, nullptr, x, D_MODEL, D_INNER);

    // hidden = gelu(x1 @ w1^T + b1)      (4096 x 4096, K=1024) -> buf0:buf1
    cvt_bf16<<<dim3(2048), blk, 0, stream>>>(w1, W8);        // 4096*1024
    gemm_bt<ACT_GELU, true, false, float, bf16>
        <<<dim3(32, 32), blk, 0, stream>>>(
        buf2, D_MODEL, W8, buf0, D_FFN, b1, (const float*)nullptr, 0, D_MODEL);

    // out0 = x1 + hidden @ w2^T + b2     (4096 x 1024, K=4096) -> d_out (f32)
    cvt_bf16<<<dim3(2048), blk, 0, stream>>>(w2, W8);        // 1024*4096
    gemm_bt<ACT_NONE, true, true, bf16, float>
        <<<dim3(8, 32), blk, 0, stream>>>(
        buf0, D_FFN, W8, out0, D_MODEL, b2, buf2, D_MODEL, D_FFN);
}

// Round 7
// 570.305 us; speedup vs baseline: 2.4246x; 1.0546x over previous
//
#include <hip/hip_runtime.h>
#include <hip/hip_bf16.h>
#include <math.h>

using bf16 = __hip_bfloat16;

typedef __attribute__((ext_vector_type(8))) short short8;
typedef __attribute__((ext_vector_type(4))) short shortx4;
typedef __attribute__((ext_vector_type(4))) float floatx4;

#define D_MODEL 1024
#define D_STATE 16
#define D_FFN   4096
#define D_INNER 2048
#define DT_RANK 64
#define BSZ     2
#define SEQ     2048
#define MROWS   (BSZ*SEQ)   /* 4096 */
#define NCHUNK  16
#define CLEN    (SEQ/NCHUNK)   /* 128 */

static __device__ __forceinline__ float bf2f(bf16 v) { return __bfloat162float(v); }
static __device__ __forceinline__ short f2s(float f) {
    bf16 h = __float2bfloat16(f);
    return *reinterpret_cast<short*>(&h);
}
static __device__ __forceinline__ float sbf(short s) {
    union { short s; bf16 h; } u; u.s = s; return __bfloat162float(u.h);
}
static __device__ __forceinline__ float rd(const bf16* p)  { return bf2f(*p); }
static __device__ __forceinline__ float rd(const float* p) { return *p; }
static __device__ __forceinline__ void  wr(bf16* p, float v)  { *p = __float2bfloat16(v); }
static __device__ __forceinline__ void  wr(float* p, float v) { *p = v; }

// async global->LDS, 16B/lane; LDS side = wave-uniform base + lane*16,
// global side = arbitrary per-lane address (gather) — exploited for swizzle.
static __device__ __forceinline__ void gload16(const bf16* g, bf16* l) {
    __builtin_amdgcn_global_load_lds(
        (const __attribute__((address_space(1))) void*)g,
        (__attribute__((address_space(3))) void*)l, 16, 0, 0);
}

// ---------------------------------------------------------------------------
// GEMM: C[M,N] = act(A[M,K] @ W[N,K]^T + bias) (+ resid). bf16 in, f32 accum.
// BK=64, XOR-swizzled LDS (col-block k8 of row m stored at slot k8^(m&7)):
// staging is 8 gload16/wave, fragment ds_read_b128 are bank-uniform.
// Optional second (W2,C2) target for by >= mtiles (fused sibling GEMM).
// XCD column-band swizzle when gridDim.x % 8 == 0.
// ---------------------------------------------------------------------------
#define BK 64

enum { ACT_NONE = 0, ACT_GELU = 1, ACT_SOFTPLUS = 2 };

template<int ACT, bool HAS_BIAS, bool HAS_RES, typename TR, typename TC>
__global__ __launch_bounds__(256)
void gemm_bt(const bf16* __restrict__ A, int lda,
             const bf16* __restrict__ W, int ldw,
             TC* __restrict__ C, int ldc,
             const float* __restrict__ bias,
             const TR* __restrict__ resid, int ldr,
             int K,
             const bf16* __restrict__ W2, TC* __restrict__ C2, int mtiles)
{
    __shared__ __align__(16) bf16 As[128 * BK];
    __shared__ __align__(16) bf16 Bs[128 * BK];

    const int tid  = threadIdx.x;
    const int lane = tid & 63;
    const int wid  = tid >> 6;
    const int wm   = wid >> 1;
    const int wn   = wid & 1;
    const int quad = lane >> 4;
    const int lrow = lane & 15;

    // XCD band swizzle (bijective remap; gx in {8,16,32})
    int bx = blockIdx.x, by = blockIdx.y;
    const int gx = gridDim.x;
    if ((gx & 7) == 0) {
        int id = by * gx + bx;
        int bw = gx >> 3;
        int band = id & 7, s = id >> 3;
        bx = band * bw + (s % bw);
        by = s / bw;
    }
    if (by >= mtiles) { by -= mtiles; W = W2; C = C2; }

    const long m0 = (long)by * 128;
    const long n0 = (long)bx * 128;

    // staging: wave w stages groups g0..g0+3 of A and of B (8 rows x 64 each)
    const int rsub = lane >> 3;               // row within group
    const int k8   = (lane & 7) ^ rsub;       // swizzled col-block
    const int g0   = wid * 4;

    const bf16* Ag[4]; const bf16* Wg[4];
    #pragma unroll
    for (int j = 0; j < 4; j++) {
        Ag[j] = A + (m0 + 8 * (g0 + j) + rsub) * (long)lda + k8 * 8;
        Wg[j] = W + (n0 + 8 * (g0 + j) + rsub) * (long)ldw + k8 * 8;
    }

    // fragment LDS col offsets (elems): slot = (kk*4+quad) ^ (lrow&7)
    const int xorl  = lrow & 7;
    const int coK0  = ((quad)     ^ xorl) * 8;
    const int coK1  = ((quad + 4) ^ xorl) * 8;

    floatx4 acc[4][4] = {};

    for (int k0 = 0; k0 < K; k0 += BK) {
        __syncthreads();                 // LDS safe to overwrite
        #pragma unroll
        for (int j = 0; j < 4; j++) {
            gload16(Ag[j] + k0, As + (g0 + j) * 512);
            gload16(Wg[j] + k0, Bs + (g0 + j) * 512);
        }
        __syncthreads();                 // drain + barrier

        #pragma unroll
        for (int kk = 0; kk < 2; kk++) {
            const int co = kk ? coK1 : coK0;
            short8 af[4], bfv[4];
            #pragma unroll
            for (int i = 0; i < 4; i++)
                af[i] = *(const short8*)(As + (wm * 64 + i * 16 + lrow) * BK + co);
            #pragma unroll
            for (int j = 0; j < 4; j++)
                bfv[j] = *(const short8*)(Bs + (wn * 64 + j * 16 + lrow) * BK + co);
            #pragma unroll
            for (int i = 0; i < 4; i++)
                #pragma unroll
                for (int j = 0; j < 4; j++)
                    acc[i][j] = __builtin_amdgcn_mfma_f32_16x16x32_bf16(af[i], bfv[j], acc[i][j], 0, 0, 0);
        }
    }

    // epilogue: D row = quad*4 + r, col = lrow (verified m89 C/D layout)
    #pragma unroll
    for (int j = 0; j < 4; j++) {
        const long col = n0 + wn * 64 + j * 16 + lrow;
        float bv = HAS_BIAS ? bias[col] : 0.0f;
        #pragma unroll
        for (int i = 0; i < 4; i++) {
            #pragma unroll
            for (int r = 0; r < 4; r++) {
                const long row = m0 + wm * 64 + i * 16 + quad * 4 + r;
                float v = acc[i][j][r] + bv;
                if (ACT == ACT_GELU)     v = 0.5f * v * (1.0f + erff(v * 0.70710678118f));
                if (ACT == ACT_SOFTPLUS) v = (v > 20.0f) ? v : log1pf(__expf(v));
                if (HAS_RES) v += rd(resid + row * (long)ldr + col);
                wr(C + row * (long)ldc + col, v);
            }
        }
    }
}

// ---------------------------------------------------------------------------
// f32 -> bf16 convert, 8 elems/thread
// ---------------------------------------------------------------------------
__global__ __launch_bounds__(256)
void cvt_bf16(const float* __restrict__ src, bf16* __restrict__ dst)
{
    long i = (long)blockIdx.x * 256 + threadIdx.x;
    float4 a = *((const float4*)src + i * 2);
    float4 b = *((const float4*)src + i * 2 + 1);
    short8 r;
    r[0] = f2s(a.x); r[1] = f2s(a.y); r[2] = f2s(a.z); r[3] = f2s(a.w);
    r[4] = f2s(b.x); r[5] = f2s(b.y); r[6] = f2s(b.z); r[7] = f2s(b.w);
    *(short8*)(dst + i * 8) = r;
}

// ---------------------------------------------------------------------------
// depthwise causal conv (K=3) + bias + silu
// ---------------------------------------------------------------------------
__global__ __launch_bounds__(256)
void conv_silu(const bf16* __restrict__ xpre, const float* __restrict__ cw,
               const float* __restrict__ cb, bf16* __restrict__ xp)
{
    long i = (long)blockIdx.x * 256 + threadIdx.x;
    int  d  = (int)(i & (D_INNER - 1));
    long bl = i >> 11;
    long l  = bl & (SEQ - 1);

    float w0 = cw[d * 3 + 0];
    float w1 = cw[d * 3 + 1];
    float w2 = cw[d * 3 + 2];
    float acc = cb[d] + w2 * bf2f(xpre[i]);
    if (l >= 1) acc += w1 * bf2f(xpre[i - D_INNER]);
    if (l >= 2) acc += w0 * bf2f(xpre[i - 2 * D_INNER]);
    float s = acc / (1.0f + __expf(-acc));
    xp[i] = __float2bfloat16(s);
}

// ---------------------------------------------------------------------------
// pad x_proj_w (96,2048) f32 -> (128,2048) bf16 with zero rows
// ---------------------------------------------------------------------------
__global__ __launch_bounds__(256)
void pad_xproj(const float* __restrict__ src, bf16* __restrict__ dst)
{
    int i = blockIdx.x * 256 + threadIdx.x;
    int row = i >> 11, col = i & 2047;
    dst[i] = (row < 96) ? __float2bfloat16(src[row * 2048 + col])
                        : __float2bfloat16(0.0f);
}

// ---------------------------------------------------------------------------
// Chunked SSM scan (verified rounds 4-6)
// ---------------------------------------------------------------------------
#define SROWS 16
#define SDB   64
#define SNB   (CLEN/SROWS)   /* 8 */

__global__ __launch_bounds__(256)
void scan_part(const bf16* __restrict__ dt, const bf16* __restrict__ xp,
               const bf16* __restrict__ dbc, const float* __restrict__ Alog,
               float* __restrict__ Pbuf, float* __restrict__ Qbuf)
{
    __shared__ float2 Ap[2][SROWS][SDB];   // (dt, dt*xp)
    __shared__ float  Bp[2][SROWS][16];

    const int tid  = threadIdx.x;
    const int c    = blockIdx.x & (NCHUNK - 1);
    const int dgrp = (blockIdx.x >> 4) & 31;
    const int b    = blockIdx.x >> 9;
    const int d0   = dgrp * SDB;
    const long row0 = (long)b * SEQ + (long)c * CLEN;

    const int sl  = tid >> 4;
    const int sq  = tid & 15;
    const int sd4 = sq * 4;

    const int nt = tid & 3;
    const int dl = tid >> 2;
    const int n0 = nt * 4;
    const int d  = d0 + dl;

    const float4 Av = *(const float4*)(Alog + d * 16 + n0);
    float Ad[4] = { -__expf(Av.x), -__expf(Av.y), -__expf(Av.z), -__expf(Av.w) };

    float rdt[4], rdx[4], rB;
    auto ldb = [&](int bb) {
        long row = row0 + bb * SROWS + sl;
        shortx4 dv = *(const shortx4*)(dt + row * D_INNER + d0 + sd4);
        shortx4 xv = *(const shortx4*)(xp + row * D_INNER + d0 + sd4);
        #pragma unroll
        for (int k = 0; k < 4; k++) {
            float f = sbf(dv[k]);
            rdt[k] = f;
            rdx[k] = f * sbf(xv[k]);
        }
        rB = bf2f(dbc[row * 128 + 64 + sq]);
    };
    auto stb = [&](int bb) {
        int s = bb & 1;
        #pragma unroll
        for (int k = 0; k < 4; k++)
            Ap[s][sl][sd4 + k] = make_float2(rdt[k], rdx[k]);
        Bp[s][sl][sq] = rB;
    };

    float h[4] = {0.f, 0.f, 0.f, 0.f};
    float sdt = 0.f;

    ldb(0); stb(0);
    for (int bb = 0; bb < SNB; bb++) {
        if (bb + 1 < SNB) ldb(bb + 1);
        __syncthreads();
        const int s = bb & 1;
        #pragma unroll
        for (int l = 0; l < SROWS; l++) {
            float2  a  = Ap[s][l][dl];
            floatx4 Bq = *(const floatx4*)&Bp[s][l][n0];
            sdt += a.x;
            #pragma unroll
            for (int k = 0; k < 4; k++)
                h[k] = __expf(a.x * Ad[k]) * h[k] + a.y * Bq[k];
        }
        if (bb + 1 < SNB) stb(bb + 1);
    }

    const long base = ((long)(b * NCHUNK + c) * D_INNER + d) * 16 + n0;
    floatx4 P = { __expf(Ad[0] * sdt), __expf(Ad[1] * sdt),
                  __expf(Ad[2] * sdt), __expf(Ad[3] * sdt) };
    floatx4 Q = { h[0], h[1], h[2], h[3] };
    *(floatx4*)(Pbuf + base) = P;
    *(floatx4*)(Qbuf + base) = Q;
}

__global__ __launch_bounds__(256)
void scan_combine(const float* __restrict__ Pbuf, float* __restrict__ Qbuf,
                  float* __restrict__ state)
{
    long i = (long)blockIdx.x * 256 + threadIdx.x;   // 65536 = (b,d,n)
    int  n = (int)(i & 15);
    int  d = (int)((i >> 4) & (D_INNER - 1));
    int  b = (int)(i >> 15);
    float h = 0.0f;
    #pragma unroll
    for (int c = 0; c < NCHUNK; c++) {
        const long idx = ((long)(b * NCHUNK + c) * D_INNER + d) * 16 + n;
        float P = Pbuf[idx], Q = Qbuf[idx];
        Qbuf[idx] = h;               // exclusive prefix = h_in for chunk c
        h = P * h + Q;
    }
    state[((long)b * D_INNER + d) * 16 + n] = h;
}

__global__ __launch_bounds__(256)
void scan_final(const bf16* __restrict__ dt, bf16* __restrict__ xp,
                const bf16* __restrict__ dbc, const float* __restrict__ Alog,
                const bf16* __restrict__ z, const float* __restrict__ Dp,
                const float* __restrict__ Qbuf)
{
    __shared__ float2 Ap [2][SROWS][SDB];   // (dt, dt*xp)
    __shared__ float2 BCp[2][SROWS][16];    // (B, C)
    __shared__ float2 GWp[2][SROWS][SDB];   // (g=silu(z), w=xp*Dp*g)

    const int tid  = threadIdx.x;
    const int c    = blockIdx.x & (NCHUNK - 1);
    const int dgrp = (blockIdx.x >> 4) & 31;
    const int b    = blockIdx.x >> 9;
    const int d0   = dgrp * SDB;
    const long row0 = (long)b * SEQ + (long)c * CLEN;

    const int sl  = tid >> 4;
    const int sq  = tid & 15;
    const int sd4 = sq * 4;

    const int nt = tid & 3;
    const int dl = tid >> 2;
    const int n0 = nt * 4;
    const int d  = d0 + dl;

    const float4 Av = *(const float4*)(Alog + d * 16 + n0);
    float Ad[4] = { -__expf(Av.x), -__expf(Av.y), -__expf(Av.z), -__expf(Av.w) };
    const float4 Dv = *(const float4*)(Dp + d0 + sd4);
    const float Dk[4] = { Dv.x, Dv.y, Dv.z, Dv.w };

    float rdt[4], rdx[4], rg[4], rw[4], rB, rC;
    auto ldb = [&](int bb) {
        long row = row0 + bb * SROWS + sl;
        shortx4 dv = *(const shortx4*)(dt + row * D_INNER + d0 + sd4);
        shortx4 xv = *(const shortx4*)(xp + row * D_INNER + d0 + sd4);
        shortx4 zv = *(const shortx4*)(z  + row * D_INNER + d0 + sd4);
        #pragma unroll
        for (int k = 0; k < 4; k++) {
            float f  = sbf(dv[k]);
            float xf = sbf(xv[k]);
            float zf = sbf(zv[k]);
            float g  = zf / (1.0f + __expf(-zf));
            rdt[k] = f;
            rdx[k] = f * xf;
            rg[k]  = g;
            rw[k]  = xf * Dk[k] * g;
        }
        rB = bf2f(dbc[row * 128 + 64 + sq]);
        rC = bf2f(dbc[row * 128 + 80 + sq]);
    };
    auto stb = [&](int bb) {
        int s = bb & 1;
        #pragma unroll
        for (int k = 0; k < 4; k++) {
            Ap [s][sl][sd4 + k] = make_float2(rdt[k], rdx[k]);
            GWp[s][sl][sd4 + k] = make_float2(rg[k], rw[k]);
        }
        BCp[s][sl][sq] = make_float2(rB, rC);
    };

    float h[4];
    {
        const long base = ((long)(b * NCHUNK + c) * D_INNER + d) * 16 + n0;
        floatx4 q = *(const floatx4*)(Qbuf + base);
        h[0] = q[0]; h[1] = q[1]; h[2] = q[2]; h[3] = q[3];
    }

    ldb(0); stb(0);
    for (int bb = 0; bb < SNB; bb++) {
        if (bb + 1 < SNB) ldb(bb + 1);
        __syncthreads();
        const int s = bb & 1;
        #pragma unroll
        for (int l = 0; l < SROWS; l++) {
            float2  a   = Ap[s][l][dl];
            floatx4 bc0 = *(const floatx4*)&BCp[s][l][n0];      // B0,C0,B1,C1
            floatx4 bc1 = *(const floatx4*)&BCp[s][l][n0 + 2];  // B2,C2,B3,C3
            float yv;
            h[0] = __expf(a.x * Ad[0]) * h[0] + a.y * bc0[0];
            yv   = h[0] * bc0[1];
            h[1] = __expf(a.x * Ad[1]) * h[1] + a.y * bc0[2];
            yv  += h[1] * bc0[3];
            h[2] = __expf(a.x * Ad[2]) * h[2] + a.y * bc1[0];
            yv  += h[2] * bc1[1];
            h[3] = __expf(a.x * Ad[3]) * h[3] + a.y * bc1[2];
            yv  += h[3] * bc1[3];
            yv += __shfl_xor(yv, 1);
            yv += __shfl_xor(yv, 2);
            if (nt == 0) {
                float2 gw = GWp[s][l][dl];
                float out = yv * gw.x + gw.y;
                xp[(row0 + bb * SROWS + l) * (long)D_INNER + d0 + dl] =
                    __float2bfloat16(out);
            }
        }
        if (bb + 1 < SNB) stb(bb + 1);
    }
}

// ---------------------------------------------------------------------------
extern "C" void kernel_launch(void* const* d_in, const int* in_sizes, int n_in,
                              void* d_out, int out_size, void* d_ws, size_t ws_size,
                              hipStream_t stream)
{
    const float* x      = (const float*)d_in[0];
    const float* inw    = (const float*)d_in[1];
    const float* convw  = (const float*)d_in[2];
    const float* convb  = (const float*)d_in[3];
    const float* xprojw = (const float*)d_in[4];
    const float* dtw    = (const float*)d_in[5];
    const float* dtbias = (const float*)d_in[6];
    const float* Alog   = (const float*)d_in[7];
    const float* Dp     = (const float*)d_in[8];
    const float* outw   = (const float*)d_in[9];
    const float* w1     = (const float*)d_in[10];
    const float* b1     = (const float*)d_in[11];
    const float* w2     = (const float*)d_in[12];
    const float* b2     = (const float*)d_in[13];

    float* out0 = (float*)d_out;                     // (2,2048,1024) f32
    float* out1 = out0 + (long)MROWS * D_MODEL;      // (2,2048,16)   f32 @ +16MB

    // ws (57.5 MiB, proven): 3 act bufs + dbc + wpad + rotating weight slot
    bf16* buf0 = (bf16*)d_ws;                        // xpre -> dt -> hidden lo
    bf16* buf1 = buf0 + (long)MROWS * D_INNER;       // xp -> gated y (in-place) -> hidden hi
    bf16* buf2 = buf1 + (long)MROWS * D_INNER;       // z -> x1
    bf16* dbc  = buf2 + (long)MROWS * D_INNER;       // (4096,128), 96 cols used
    bf16* wpad = dbc  + (long)MROWS * 128;           // (128,2048)
    bf16* W8   = wpad + 128 * 2048;                  // 8 MiB rotating: inw->dtw->outw->w1->w2

    // d_out[0:16MB] as scratch (dead before final GEMM writes out0):
    float* Pbuf = (float*)d_out;                     // 4 MiB  (scan)
    float* Qbuf = Pbuf + (long)BSZ * NCHUNK * D_INNER * 16;   // 4 MiB
    bf16*  xbf  = (bf16*)((char*)d_out + 8 * 1024 * 1024);    // 8 MiB (in_proj A)

    dim3 blk(256);
    const float* nf = nullptr;

    // x, in_proj_w -> bf16
    cvt_bf16<<<dim3(2048), blk, 0, stream>>>(x, xbf);        // 4096*1024
    cvt_bf16<<<dim3(2048), blk, 0, stream>>>(inw, W8);       // 4096*1024
    pad_xproj<<<dim3(1024), blk, 0, stream>>>(xprojw, wpad);

    // fused in_proj: xpre = x@inw_lo^T -> buf0 ; z = x@inw_hi^T -> buf2
    gemm_bt<ACT_NONE, false, false, float, bf16>
        <<<dim3(16, 64), blk, 0, stream>>>(
        xbf, D_MODEL, W8, D_MODEL, buf0, D_INNER, nullptr, nf, 0, D_MODEL,
        W8 + (long)D_INNER * D_MODEL, buf2, 32);

    // xp = silu(causal_conv(xpre) + conv_b)
    conv_silu<<<dim3(32768), blk, 0, stream>>>(buf0, convw, convb, buf1);

    // dbc = xp @ x_proj_w^T              (4096 x 128pad, K=2048)
    gemm_bt<ACT_NONE, false, false, float, bf16>
        <<<dim3(1, 32), blk, 0, stream>>>(
        buf1, D_INNER, wpad, D_INNER, dbc, 128, nullptr, nf, 0, D_INNER,
        wpad, dbc, 1000);

    // dt = softplus(dbc[:, :64] @ dt_proj_w^T + dt_proj_b)   (4096 x 2048, K=64)
    cvt_bf16<<<dim3(64), blk, 0, stream>>>(dtw, W8);         // 2048*64
    gemm_bt<ACT_SOFTPLUS, true, false, float, bf16>
        <<<dim3(16, 32), blk, 0, stream>>>(
        dbc, 128, W8, DT_RANK, buf0, D_INNER, dtbias, nf, 0, DT_RANK,
        W8, buf0, 1000);

    // chunked scan: phase1 -> combine (writes state) -> phase3 (gated y in buf1)
    scan_part<<<dim3(BSZ * NCHUNK * (D_INNER / SDB)), blk, 0, stream>>>(
        buf0, buf1, dbc, Alog, Pbuf, Qbuf);
    scan_combine<<<dim3(256), blk, 0, stream>>>(Pbuf, Qbuf, out1);
    scan_final<<<dim3(BSZ * NCHUNK * (D_INNER / SDB)), blk, 0, stream>>>(
        buf0, buf1, dbc, Alog, buf2, Dp, Qbuf);

    // x1 = x + y @ out_proj_w^T          (4096 x 1024, K=2048) -> buf2
    cvt_bf16<<<dim3(1024), blk, 0, stream>>>(outw, W8);      // 1024*2048
    gemm_bt<ACT_NONE, false, true, float, bf16>
        <<<dim3(8, 32), blk, 0, stream>>>(
        buf1, D_INNER, W8, D_INNER, buf2, D_MODEL, nullptr, x, D_MODEL, D_INNER,
        W8, buf2, 1000);

    // hidden = gelu(x1 @ w1^T + b1)      (4096 x 4096, K=1024) -> buf0:buf1
    cvt_bf16<<<dim3(2048), blk, 0, stream>>>(w1, W8);        // 4096*1024
    gemm_bt<ACT_GELU, true, false, float, bf16>
        <<<dim3(32, 32), blk, 0, stream>>>(
        buf2, D_MODEL, W8, D_MODEL, buf0, D_FFN, b1, nf, 0, D_MODEL,
        W8, buf0, 1000);

    // out0 = x1 + hidden @ w2^T + b2     (4096 x 1024, K=4096) -> d_out (f32)
    cvt_bf16<<<dim3(2048), blk, 0, stream>>>(w2, W8);        // 1024*4096
    gemm_bt<ACT_NONE, true, true, bf16, float>
        <<<dim3(8, 32), blk, 0, stream>>>(
        buf0, D_FFN, W8, D_FFN, out0, D_MODEL, b2, buf2, D_MODEL, D_FFN,
        W8, out0, 1000);
}

// Round 8
// 525.832 us; speedup vs baseline: 2.6296x; 1.0846x over previous
//
#include <hip/hip_runtime.h>
#include <hip/hip_bf16.h>
#include <math.h>

using bf16 = __hip_bfloat16;

typedef __attribute__((ext_vector_type(8))) short short8;
typedef __attribute__((ext_vector_type(4))) short shortx4;
typedef __attribute__((ext_vector_type(4))) float floatx4;

#define D_MODEL 1024
#define D_STATE 16
#define D_FFN   4096
#define D_INNER 2048
#define DT_RANK 64
#define BSZ     2
#define SEQ     2048
#define MROWS   (BSZ*SEQ)   /* 4096 */
#define NCHUNK  16
#define CLEN    (SEQ/NCHUNK)   /* 128 */

static __device__ __forceinline__ float bf2f(bf16 v) { return __bfloat162float(v); }
static __device__ __forceinline__ short f2s(float f) {
    bf16 h = __float2bfloat16(f);
    return *reinterpret_cast<short*>(&h);
}
static __device__ __forceinline__ float sbf(short s) {
    union { short s; bf16 h; } u; u.s = s; return __bfloat162float(u.h);
}
static __device__ __forceinline__ float rd(const bf16* p)  { return bf2f(*p); }
static __device__ __forceinline__ float rd(const float* p) { return *p; }
static __device__ __forceinline__ void  wr(bf16* p, float v)  { *p = __float2bfloat16(v); }
static __device__ __forceinline__ void  wr(float* p, float v) { *p = v; }

// s_waitcnt immediate (gfx9 enc): lgkmcnt(0) only — vmcnt/expcnt no-wait.
#define WAIT_LGKM0 0xC07F

// ---------------------------------------------------------------------------
// GEMM: C[M,N] = act(A[M,K] @ W[N,K]^T + bias) (+ resid). bf16 in, f32 accum.
// AITER-style pipelined K-loop: BK=32, register-staged (global->VGPR one tile
// ahead, in flight across the compute phase), ds_write with compiler's
// fine-grained vmcnt, RAW s_barrier (no vmcnt(0) drain), swizzled LDS stores
// (2-way-free bank pattern). 4 waves x (4x4) mfma_f32_16x16x32_bf16.
// Optional second (W2,C2) target for by >= mtiles; XCD band swizzle.
// ---------------------------------------------------------------------------
#define BK 32

enum { ACT_NONE = 0, ACT_GELU = 1, ACT_SOFTPLUS = 2 };

template<int ACT, bool HAS_BIAS, bool HAS_RES, typename TR, typename TC>
__global__ __launch_bounds__(256)
void gemm_bt(const bf16* __restrict__ A, int lda,
             const bf16* __restrict__ W, int ldw,
             TC* __restrict__ C, int ldc,
             const float* __restrict__ bias,
             const TR* __restrict__ resid, int ldr,
             int K,
             const bf16* __restrict__ W2, TC* __restrict__ C2, int mtiles)
{
    __shared__ __align__(16) bf16 As[128 * BK];   // 8 KB
    __shared__ __align__(16) bf16 Bs[128 * BK];   // 8 KB

    const int tid  = threadIdx.x;
    const int lane = tid & 63;
    const int wid  = tid >> 6;
    const int wm   = wid >> 1;
    const int wn   = wid & 1;
    const int quad = lane >> 4;
    const int lrow = lane & 15;

    // XCD band swizzle (bijective; gx multiple of 8)
    int bx = blockIdx.x, by = blockIdx.y;
    const int gx = gridDim.x;
    if ((gx & 7) == 0) {
        int id = by * gx + bx;
        int bw = gx >> 3;
        int band = id & 7, s = id >> 3;
        bx = band * bw + (s % bw);
        by = s / bw;
    }
    if (by >= mtiles) { by -= mtiles; W = W2; C = C2; }

    const long m0 = (long)by * 128;
    const long n0 = (long)bx * 128;

    // register staging: wave w loads rows [32w,32w+32) of the A and B tiles.
    const int rlg = lane >> 2;                 // 0..15 row within 16-row group
    const int kfo = (lane & 3) * 8;            // plain coalesced col offset
    const int g0  = wid * 2;
    const bf16* Ag0 = A + (m0 + (g0 + 0) * 16 + rlg) * (long)lda + kfo;
    const bf16* Ag1 = A + (m0 + (g0 + 1) * 16 + rlg) * (long)lda + kfo;
    const bf16* Wg0 = W + (n0 + (g0 + 0) * 16 + rlg) * (long)ldw + kfo;
    const bf16* Wg1 = W + (n0 + (g0 + 1) * 16 + rlg) * (long)ldw + kfo;

    // swizzled LDS store offsets: row*32 + ((lane&3) ^ ((rlg>>1)&3))*8
    const int slot = (((lane & 3) ^ ((rlg >> 1) & 3))) * 8;
    const int so0  = ((g0 + 0) * 16 + rlg) * 32 + slot;
    const int so1  = ((g0 + 1) * 16 + rlg) * 32 + slot;

    // fragment read col offset (matches store swizzle; 2-way banks = free)
    const int co = ((quad ^ ((lrow >> 1) & 3))) * 8;

    floatx4 acc[4][4] = {};

    // prologue: tile 0 -> regs
    short8 ra0 = *(const short8*)Ag0;
    short8 ra1 = *(const short8*)Ag1;
    short8 rb0 = *(const short8*)Wg0;
    short8 rb1 = *(const short8*)Wg1;

    const int nit = K / BK;
    for (int it = 0; it < nit; ++it) {
        // stage tile it regs -> LDS (compiler emits fine-grained vmcnt here)
        *(short8*)(As + so0) = ra0;
        *(short8*)(As + so1) = ra1;
        *(short8*)(Bs + so0) = rb0;
        *(short8*)(Bs + so1) = rb1;
        __builtin_amdgcn_s_waitcnt(WAIT_LGKM0);   // my ds_writes visible
        __builtin_amdgcn_s_barrier();             // all writes visible (no vm drain)

        if (it + 1 < nit) {                       // issue next tile; stays in flight
            const long ko = (long)(it + 1) * BK;
            ra0 = *(const short8*)(Ag0 + ko);
            ra1 = *(const short8*)(Ag1 + ko);
            rb0 = *(const short8*)(Wg0 + ko);
            rb1 = *(const short8*)(Wg1 + ko);
        }

        short8 af[4], bfv[4];
        #pragma unroll
        for (int i = 0; i < 4; i++)
            af[i] = *(const short8*)(As + (wm * 64 + i * 16 + lrow) * BK + co);
        #pragma unroll
        for (int j = 0; j < 4; j++)
            bfv[j] = *(const short8*)(Bs + (wn * 64 + j * 16 + lrow) * BK + co);
        #pragma unroll
        for (int i = 0; i < 4; i++)
            #pragma unroll
            for (int j = 0; j < 4; j++)
                acc[i][j] = __builtin_amdgcn_mfma_f32_16x16x32_bf16(af[i], bfv[j], acc[i][j], 0, 0, 0);

        __builtin_amdgcn_s_barrier();             // all reads done before overwrite
    }

    // epilogue: D row = quad*4 + r, col = lrow (verified m89 C/D layout)
    #pragma unroll
    for (int j = 0; j < 4; j++) {
        const long col = n0 + wn * 64 + j * 16 + lrow;
        float bv = HAS_BIAS ? bias[col] : 0.0f;
        #pragma unroll
        for (int i = 0; i < 4; i++) {
            #pragma unroll
            for (int r = 0; r < 4; r++) {
                const long row = m0 + wm * 64 + i * 16 + quad * 4 + r;
                float v = acc[i][j][r] + bv;
                if (ACT == ACT_GELU)     v = 0.5f * v * (1.0f + erff(v * 0.70710678118f));
                if (ACT == ACT_SOFTPLUS) v = (v > 20.0f) ? v : log1pf(__expf(v));
                if (HAS_RES) v += rd(resid + row * (long)ldr + col);
                wr(C + row * (long)ldc + col, v);
            }
        }
    }
}

// ---------------------------------------------------------------------------
// fused weight/input prep (f32 -> bf16), 8 elems/thread
// ---------------------------------------------------------------------------
static __device__ __forceinline__ void cvt8(const float* __restrict__ s,
                                            bf16* __restrict__ d, long i)
{
    float4 a = *((const float4*)s + i * 2);
    float4 b = *((const float4*)s + i * 2 + 1);
    short8 r;
    r[0] = f2s(a.x); r[1] = f2s(a.y); r[2] = f2s(a.z); r[3] = f2s(a.w);
    r[4] = f2s(b.x); r[5] = f2s(b.y); r[6] = f2s(b.z); r[7] = f2s(b.w);
    *(short8*)(d + i * 8) = r;
}

__global__ __launch_bounds__(256)
void prep1(const float* __restrict__ x, const float* __restrict__ inw,
           const float* __restrict__ dtw, const float* __restrict__ xprojw,
           bf16* __restrict__ xbf, bf16* __restrict__ inwb,
           bf16* __restrict__ dtwb, bf16* __restrict__ wpad)
{
    const int bid = blockIdx.x;
    const long t = threadIdx.x;
    if (bid < 2048)      cvt8(x,   xbf,  (long)bid * 256 + t);
    else if (bid < 4096) cvt8(inw, inwb, (long)(bid - 2048) * 256 + t);
    else if (bid < 4160) cvt8(dtw, dtwb, (long)(bid - 4096) * 256 + t);
    else {
        long i = (long)(bid - 4160) * 256 + t;   // 8-elem groups of wpad (128x2048)
        int row = (int)(i >> 8);
        int c8  = (int)(i & 255) * 8;
        short8 r = {0, 0, 0, 0, 0, 0, 0, 0};
        if (row < 96) {
            const float* s = xprojw + (long)row * 2048 + c8;
            float4 a = *(const float4*)s, b = *(const float4*)(s + 4);
            r[0] = f2s(a.x); r[1] = f2s(a.y); r[2] = f2s(a.z); r[3] = f2s(a.w);
            r[4] = f2s(b.x); r[5] = f2s(b.y); r[6] = f2s(b.z); r[7] = f2s(b.w);
        }
        *(short8*)(wpad + (long)row * 2048 + c8) = r;
    }
}

__global__ __launch_bounds__(256)
void prep2(const float* __restrict__ outw, const float* __restrict__ w1,
           const float* __restrict__ w2,
           bf16* __restrict__ outwb, bf16* __restrict__ w1b,
           bf16* __restrict__ w2b)
{
    const int bid = blockIdx.x;
    const long t = threadIdx.x;
    if (bid < 1024)      cvt8(outw, outwb, (long)bid * 256 + t);
    else if (bid < 3072) cvt8(w1, w1b, (long)(bid - 1024) * 256 + t);
    else                 cvt8(w2, w2b, (long)(bid - 3072) * 256 + t);
}

// ---------------------------------------------------------------------------
// depthwise causal conv (K=3) + bias + silu
// ---------------------------------------------------------------------------
__global__ __launch_bounds__(256)
void conv_silu(const bf16* __restrict__ xpre, const float* __restrict__ cw,
               const float* __restrict__ cb, bf16* __restrict__ xp)
{
    long i = (long)blockIdx.x * 256 + threadIdx.x;
    int  d  = (int)(i & (D_INNER - 1));
    long bl = i >> 11;
    long l  = bl & (SEQ - 1);

    float w0 = cw[d * 3 + 0];
    float w1 = cw[d * 3 + 1];
    float w2 = cw[d * 3 + 2];
    float acc = cb[d] + w2 * bf2f(xpre[i]);
    if (l >= 1) acc += w1 * bf2f(xpre[i - D_INNER]);
    if (l >= 2) acc += w0 * bf2f(xpre[i - 2 * D_INNER]);
    float s = acc / (1.0f + __expf(-acc));
    xp[i] = __float2bfloat16(s);
}

// ---------------------------------------------------------------------------
// Chunked SSM scan (verified rounds 4-7)
// ---------------------------------------------------------------------------
#define SROWS 16
#define SDB   64
#define SNB   (CLEN/SROWS)   /* 8 */

__global__ __launch_bounds__(256)
void scan_part(const bf16* __restrict__ dt, const bf16* __restrict__ xp,
               const bf16* __restrict__ dbc, const float* __restrict__ Alog,
               float* __restrict__ Pbuf, float* __restrict__ Qbuf)
{
    __shared__ float2 Ap[2][SROWS][SDB];   // (dt, dt*xp)
    __shared__ float  Bp[2][SROWS][16];

    const int tid  = threadIdx.x;
    const int c    = blockIdx.x & (NCHUNK - 1);
    const int dgrp = (blockIdx.x >> 4) & 31;
    const int b    = blockIdx.x >> 9;
    const int d0   = dgrp * SDB;
    const long row0 = (long)b * SEQ + (long)c * CLEN;

    const int sl  = tid >> 4;
    const int sq  = tid & 15;
    const int sd4 = sq * 4;

    const int nt = tid & 3;
    const int dl = tid >> 2;
    const int n0 = nt * 4;
    const int d  = d0 + dl;

    const float4 Av = *(const float4*)(Alog + d * 16 + n0);
    float Ad[4] = { -__expf(Av.x), -__expf(Av.y), -__expf(Av.z), -__expf(Av.w) };

    float rdt[4], rdx[4], rB;
    auto ldb = [&](int bb) {
        long row = row0 + bb * SROWS + sl;
        shortx4 dv = *(const shortx4*)(dt + row * D_INNER + d0 + sd4);
        shortx4 xv = *(const shortx4*)(xp + row * D_INNER + d0 + sd4);
        #pragma unroll
        for (int k = 0; k < 4; k++) {
            float f = sbf(dv[k]);
            rdt[k] = f;
            rdx[k] = f * sbf(xv[k]);
        }
        rB = bf2f(dbc[row * 128 + 64 + sq]);
    };
    auto stb = [&](int bb) {
        int s = bb & 1;
        #pragma unroll
        for (int k = 0; k < 4; k++)
            Ap[s][sl][sd4 + k] = make_float2(rdt[k], rdx[k]);
        Bp[s][sl][sq] = rB;
    };

    float h[4] = {0.f, 0.f, 0.f, 0.f};
    float sdt = 0.f;

    ldb(0); stb(0);
    for (int bb = 0; bb < SNB; bb++) {
        if (bb + 1 < SNB) ldb(bb + 1);
        __syncthreads();
        const int s = bb & 1;
        #pragma unroll
        for (int l = 0; l < SROWS; l++) {
            float2  a  = Ap[s][l][dl];
            floatx4 Bq = *(const floatx4*)&Bp[s][l][n0];
            sdt += a.x;
            #pragma unroll
            for (int k = 0; k < 4; k++)
                h[k] = __expf(a.x * Ad[k]) * h[k] + a.y * Bq[k];
        }
        if (bb + 1 < SNB) stb(bb + 1);
    }

    const long base = ((long)(b * NCHUNK + c) * D_INNER + d) * 16 + n0;
    floatx4 P = { __expf(Ad[0] * sdt), __expf(Ad[1] * sdt),
                  __expf(Ad[2] * sdt), __expf(Ad[3] * sdt) };
    floatx4 Q = { h[0], h[1], h[2], h[3] };
    *(floatx4*)(Pbuf + base) = P;
    *(floatx4*)(Qbuf + base) = Q;
}

__global__ __launch_bounds__(256)
void scan_combine(const float* __restrict__ Pbuf, float* __restrict__ Qbuf,
                  float* __restrict__ state)
{
    long i = (long)blockIdx.x * 256 + threadIdx.x;   // 65536 = (b,d,n)
    int  n = (int)(i & 15);
    int  d = (int)((i >> 4) & (D_INNER - 1));
    int  b = (int)(i >> 15);
    float h = 0.0f;
    #pragma unroll
    for (int c = 0; c < NCHUNK; c++) {
        const long idx = ((long)(b * NCHUNK + c) * D_INNER + d) * 16 + n;
        float P = Pbuf[idx], Q = Qbuf[idx];
        Qbuf[idx] = h;               // exclusive prefix = h_in for chunk c
        h = P * h + Q;
    }
    state[((long)b * D_INNER + d) * 16 + n] = h;
}

__global__ __launch_bounds__(256)
void scan_final(const bf16* __restrict__ dt, bf16* __restrict__ xp,
                const bf16* __restrict__ dbc, const float* __restrict__ Alog,
                const bf16* __restrict__ z, const float* __restrict__ Dp,
                const float* __restrict__ Qbuf)
{
    __shared__ float2 Ap [2][SROWS][SDB];   // (dt, dt*xp)
    __shared__ float2 BCp[2][SROWS][16];    // (B, C)
    __shared__ float2 GWp[2][SROWS][SDB];   // (g=silu(z), w=xp*Dp*g)

    const int tid  = threadIdx.x;
    const int c    = blockIdx.x & (NCHUNK - 1);
    const int dgrp = (blockIdx.x >> 4) & 31;
    const int b    = blockIdx.x >> 9;
    const int d0   = dgrp * SDB;
    const long row0 = (long)b * SEQ + (long)c * CLEN;

    const int sl  = tid >> 4;
    const int sq  = tid & 15;
    const int sd4 = sq * 4;

    const int nt = tid & 3;
    const int dl = tid >> 2;
    const int n0 = nt * 4;
    const int d  = d0 + dl;

    const float4 Av = *(const float4*)(Alog + d * 16 + n0);
    float Ad[4] = { -__expf(Av.x), -__expf(Av.y), -__expf(Av.z), -__expf(Av.w) };
    const float4 Dv = *(const float4*)(Dp + d0 + sd4);
    const float Dk[4] = { Dv.x, Dv.y, Dv.z, Dv.w };

    float rdt[4], rdx[4], rg[4], rw[4], rB, rC;
    auto ldb = [&](int bb) {
        long row = row0 + bb * SROWS + sl;
        shortx4 dv = *(const shortx4*)(dt + row * D_INNER + d0 + sd4);
        shortx4 xv = *(const shortx4*)(xp + row * D_INNER + d0 + sd4);
        shortx4 zv = *(const shortx4*)(z  + row * D_INNER + d0 + sd4);
        #pragma unroll
        for (int k = 0; k < 4; k++) {
            float f  = sbf(dv[k]);
            float xf = sbf(xv[k]);
            float zf = sbf(zv[k]);
            float g  = zf / (1.0f + __expf(-zf));
            rdt[k] = f;
            rdx[k] = f * xf;
            rg[k]  = g;
            rw[k]  = xf * Dk[k] * g;
        }
        rB = bf2f(dbc[row * 128 + 64 + sq]);
        rC = bf2f(dbc[row * 128 + 80 + sq]);
    };
    auto stb = [&](int bb) {
        int s = bb & 1;
        #pragma unroll
        for (int k = 0; k < 4; k++) {
            Ap [s][sl][sd4 + k] = make_float2(rdt[k], rdx[k]);
            GWp[s][sl][sd4 + k] = make_float2(rg[k], rw[k]);
        }
        BCp[s][sl][sq] = make_float2(rB, rC);
    };

    float h[4];
    {
        const long base = ((long)(b * NCHUNK + c) * D_INNER + d) * 16 + n0;
        floatx4 q = *(const floatx4*)(Qbuf + base);
        h[0] = q[0]; h[1] = q[1]; h[2] = q[2]; h[3] = q[3];
    }

    ldb(0); stb(0);
    for (int bb = 0; bb < SNB; bb++) {
        if (bb + 1 < SNB) ldb(bb + 1);
        __syncthreads();
        const int s = bb & 1;
        #pragma unroll
        for (int l = 0; l < SROWS; l++) {
            float2  a   = Ap[s][l][dl];
            floatx4 bc0 = *(const floatx4*)&BCp[s][l][n0];      // B0,C0,B1,C1
            floatx4 bc1 = *(const floatx4*)&BCp[s][l][n0 + 2];  // B2,C2,B3,C3
            float yv;
            h[0] = __expf(a.x * Ad[0]) * h[0] + a.y * bc0[0];
            yv   = h[0] * bc0[1];
            h[1] = __expf(a.x * Ad[1]) * h[1] + a.y * bc0[2];
            yv  += h[1] * bc0[3];
            h[2] = __expf(a.x * Ad[2]) * h[2] + a.y * bc1[0];
            yv  += h[2] * bc1[1];
            h[3] = __expf(a.x * Ad[3]) * h[3] + a.y * bc1[2];
            yv  += h[3] * bc1[3];
            yv += __shfl_xor(yv, 1);
            yv += __shfl_xor(yv, 2);
            if (nt == 0) {
                float2 gw = GWp[s][l][dl];
                float out = yv * gw.x + gw.y;
                xp[(row0 + bb * SROWS + l) * (long)D_INNER + d0 + dl] =
                    __float2bfloat16(out);
            }
        }
        if (bb + 1 < SNB) stb(bb + 1);
    }
}

// ---------------------------------------------------------------------------
extern "C" void kernel_launch(void* const* d_in, const int* in_sizes, int n_in,
                              void* d_out, int out_size, void* d_ws, size_t ws_size,
                              hipStream_t stream)
{
    const float* x      = (const float*)d_in[0];
    const float* inw    = (const float*)d_in[1];
    const float* convw  = (const float*)d_in[2];
    const float* convb  = (const float*)d_in[3];
    const float* xprojw = (const float*)d_in[4];
    const float* dtw    = (const float*)d_in[5];
    const float* dtbias = (const float*)d_in[6];
    const float* Alog   = (const float*)d_in[7];
    const float* Dp     = (const float*)d_in[8];
    const float* outw   = (const float*)d_in[9];
    const float* w1     = (const float*)d_in[10];
    const float* b1     = (const float*)d_in[11];
    const float* w2     = (const float*)d_in[12];
    const float* b2     = (const float*)d_in[13];

    float* out0 = (float*)d_out;                     // (2,2048,1024) f32 @ [0,16MiB)
    float* out1 = out0 + (long)MROWS * D_MODEL;      // (2,2048,16)   f32 @ [16,16.25MiB)

    // ws (57.5 MiB, proven): 3 act bufs + dbc + wpad + W8 (inw -> w2)
    bf16* buf0 = (bf16*)d_ws;                        // xpre -> dt -> hidden lo
    bf16* buf1 = buf0 + (long)MROWS * D_INNER;       // xp -> gated y (in-place) -> hidden hi
    bf16* buf2 = buf1 + (long)MROWS * D_INNER;       // z -> x1
    bf16* dbc  = buf2 + (long)MROWS * D_INNER;       // (4096,128), 96 cols used
    bf16* wpad = dbc  + (long)MROWS * 128;           // (128,2048)
    bf16* W8   = wpad + 128 * 2048;                  // 8 MiB: inw (prep1) -> w2 (prep2)

    // d_out scratch overlays (each dead before its region is clobbered):
    bf16*  dtwb  = (bf16*)d_out;                               // [0,0.25M) prep1->dtGEMM; clobbered by Pbuf
    float* Pbuf  = (float*)d_out;                              // [0,4M)  scan
    float* Qbuf  = Pbuf + (long)BSZ * NCHUNK * D_INNER * 16;   // [4,8M)  scan
    bf16*  xbf   = (bf16*)((char*)d_out + 8 * 1024 * 1024);    // [8,16M) prep1->in_proj
    bf16*  w1b   = (bf16*)d_out;                               // [0,8M)  prep2->FFN1 (P/Q dead)
    bf16*  outwb = (bf16*)((char*)d_out + 8 * 1024 * 1024);    // [8,12M) prep2->out_proj (xbf dead)

    dim3 blk(256);
    const float* nf = nullptr;

    // prep1: x->xbf, inw->W8, dtw->dtwb, xprojw->wpad   (one dispatch)
    prep1<<<dim3(4288), blk, 0, stream>>>(x, inw, dtw, xprojw, xbf, W8, dtwb, wpad);

    // fused in_proj: xpre = x@inw_lo^T -> buf0 ; z = x@inw_hi^T -> buf2
    gemm_bt<ACT_NONE, false, false, float, bf16>
        <<<dim3(16, 64), blk, 0, stream>>>(
        xbf, D_MODEL, W8, D_MODEL, buf0, D_INNER, nullptr, nf, 0, D_MODEL,
        W8 + (long)D_INNER * D_MODEL, buf2, 32);

    // xp = silu(causal_conv(xpre) + conv_b)
    conv_silu<<<dim3(32768), blk, 0, stream>>>(buf0, convw, convb, buf1);

    // dbc = xp @ x_proj_w^T              (4096 x 128pad, K=2048)
    gemm_bt<ACT_NONE, false, false, float, bf16>
        <<<dim3(1, 32), blk, 0, stream>>>(
        buf1, D_INNER, wpad, D_INNER, dbc, 128, nullptr, nf, 0, D_INNER,
        wpad, dbc, 1000);

    // dt = softplus(dbc[:, :64] @ dt_proj_w^T + dt_proj_b)   (4096 x 2048, K=64)
    gemm_bt<ACT_SOFTPLUS, true, false, float, bf16>
        <<<dim3(16, 32), blk, 0, stream>>>(
        dbc, 128, dtwb, DT_RANK, buf0, D_INNER, dtbias, nf, 0, DT_RANK,
        dtwb, buf0, 1000);

    // chunked scan: phase1 -> combine (writes state) -> phase3 (gated y in buf1)
    scan_part<<<dim3(BSZ * NCHUNK * (D_INNER / SDB)), blk, 0, stream>>>(
        buf0, buf1, dbc, Alog, Pbuf, Qbuf);
    scan_combine<<<dim3(256), blk, 0, stream>>>(Pbuf, Qbuf, out1);
    scan_final<<<dim3(BSZ * NCHUNK * (D_INNER / SDB)), blk, 0, stream>>>(
        buf0, buf1, dbc, Alog, buf2, Dp, Qbuf);

    // prep2: outw->outwb, w1->w1b, w2->W8   (one dispatch; P/Q + xbf dead)
    prep2<<<dim3(5120), blk, 0, stream>>>(outw, w1, w2, outwb, w1b, W8);

    // x1 = x + y @ out_proj_w^T          (4096 x 1024, K=2048) -> buf2
    gemm_bt<ACT_NONE, false, true, float, bf16>
        <<<dim3(8, 32), blk, 0, stream>>>(
        buf1, D_INNER, outwb, D_INNER, buf2, D_MODEL, nullptr, x, D_MODEL, D_INNER,
        outwb, buf2, 1000);

    // hidden = gelu(x1 @ w1^T + b1)      (4096 x 4096, K=1024) -> buf0:buf1
    gemm_bt<ACT_GELU, true, false, float, bf16>
        <<<dim3(32, 32), blk, 0, stream>>>(
        buf2, D_MODEL, w1b, D_MODEL, buf0, D_FFN, b1, nf, 0, D_MODEL,
        w1b, buf0, 1000);

    // out0 = x1 + hidden @ w2^T + b2     (4096 x 1024, K=4096) -> d_out (f32)
    //        (clobbers w1b/outwb regions only after their last use)
    gemm_bt<ACT_NONE, true, true, bf16, float>
        <<<dim3(8, 32), blk, 0, stream>>>(
        buf0, D_FFN, W8, D_FFN, out0, D_MODEL, b2, buf2, D_MODEL, D_FFN,
        W8, out0, 1000);
}